// Round 9
// baseline (29306.567 us; speedup 1.0000x reference)
//
#include <hip/hip_runtime.h>

#define N_NODES 50000
#define N_EDGES 400000
#define EPB     128          // edges per block in fused edge MLP
#define NB_SCAN 196
#define BN_EPS  1e-5f

typedef __attribute__((ext_vector_type(8))) short s16x8;
typedef __attribute__((ext_vector_type(4))) float f32x4;

__device__ __forceinline__ unsigned short f2bf(float x) {
    unsigned u = __float_as_uint(x);
    return (unsigned short)((u + 0x7fffu + ((u >> 16) & 1u)) >> 16);
}
__device__ __forceinline__ float bf2f(unsigned short b) {
    return __uint_as_float(((unsigned)b) << 16);
}

// direct global->LDS 16B load (linear LDS dest = wave base + lane*16)
__device__ __forceinline__ void gload_lds16(const void* g, void* lds) {
    auto gp = reinterpret_cast<const __attribute__((address_space(1))) unsigned int*>(
        reinterpret_cast<uintptr_t>(g));
    auto lp = reinterpret_cast<__attribute__((address_space(3))) unsigned int*>(
        reinterpret_cast<uintptr_t>(lds));
    __builtin_amdgcn_global_load_lds(gp, lp, 16, 0, 0);
}

// ---------------- utility ----------------
__global__ void zero_i32(int* p, int n) {
    int i = blockIdx.x * blockDim.x + threadIdx.x;
    if (i < n) p[i] = 0;
}
__global__ void zero_f32(float* p, int n) {
    int i = blockIdx.x * blockDim.x + threadIdx.x;
    if (i < n) p[i] = 0.0f;
}
__global__ void count_deg(const int* __restrict__ dst, int* __restrict__ counts) {
    int e = blockIdx.x * blockDim.x + threadIdx.x;
    if (e < N_EDGES) atomicAdd(&counts[dst[e]], 1);
}
__global__ void isd_kernel(const int* __restrict__ counts, float* __restrict__ isd) {
    int i = blockIdx.x * blockDim.x + threadIdx.x;
    if (i < N_NODES) isd[i] = rsqrtf(1.0f + (float)counts[i]);
}

// ---------------- 3-phase scan ----------------
__global__ __launch_bounds__(256) void scan_reduce(const int* __restrict__ counts,
                                                   int* __restrict__ bsum) {
    __shared__ int sh[256];
    int t = threadIdx.x, b = blockIdx.x;
    int i = b * 256 + t;
    sh[t] = (i < N_NODES) ? counts[i] : 0;
    __syncthreads();
    for (int o = 128; o > 0; o >>= 1) {
        if (t < o) sh[t] += sh[t + o];
        __syncthreads();
    }
    if (t == 0) bsum[b] = sh[0];
}
__global__ __launch_bounds__(256) void scan_tops(const int* __restrict__ bsum,
                                                 int* __restrict__ boff, int nb,
                                                 int* __restrict__ total_out) {
    __shared__ int sh[256];
    int t = threadIdx.x;
    int v = (t < nb) ? bsum[t] : 0;
    sh[t] = v;
    __syncthreads();
    for (int o = 1; o < 256; o <<= 1) {
        int a = (t >= o) ? sh[t - o] : 0;
        __syncthreads();
        sh[t] += a;
        __syncthreads();
    }
    if (t < nb) boff[t] = sh[t] - v;
    if (t == 255) *total_out = sh[255];
}
__global__ __launch_bounds__(256) void scan_final(const int* __restrict__ counts,
                                                  const int* __restrict__ boff,
                                                  int* __restrict__ offsets) {
    __shared__ int sh[256];
    int t = threadIdx.x, b = blockIdx.x;
    int i = b * 256 + t;
    int v = (i < N_NODES) ? counts[i] : 0;
    sh[t] = v;
    __syncthreads();
    for (int o = 1; o < 256; o <<= 1) {
        int a = (t >= o) ? sh[t - o] : 0;
        __syncthreads();
        sh[t] += a;
        __syncthreads();
    }
    if (i < N_NODES) offsets[i] = boff[b] + sh[t] - v;
}

// packed CSR entry: (src, norm) as int2; also dst and orig-edge-id per CSR slot
__global__ void fill_csr(const int* __restrict__ src, const int* __restrict__ dst,
                         const float* __restrict__ isd, const int* __restrict__ offsets,
                         int* __restrict__ cursor, int2* __restrict__ pk,
                         int* __restrict__ edstA, int* __restrict__ eorigA) {
    int e = blockIdx.x * blockDim.x + threadIdx.x;
    if (e >= N_EDGES) return;
    int s = src[e], d = dst[e];
    int pos = offsets[d] + atomicAdd(&cursor[d], 1);
    pk[pos] = make_int2(s, __float_as_int(isd[s] * isd[d]));
    edstA[pos] = d;
    eorigA[pos] = e;
}

// ---------------- conversions ----------------
__global__ void conv_f32_bf16(const float* __restrict__ in, unsigned short* __restrict__ out,
                              int n4) {
    int i = blockIdx.x * blockDim.x + threadIdx.x;
    if (i >= n4) return;
    float4 v = ((const float4*)in)[i];
    unsigned short o0 = f2bf(v.x), o1 = f2bf(v.y), o2 = f2bf(v.z), o3 = f2bf(v.w);
    ((uint2*)out)[i] = make_uint2(((unsigned)o1 << 16) | o0, ((unsigned)o3 << 16) | o2);
}

// all 11 weight transposes (fp32 [K][N] -> bf16 [N][K]) in one dispatch
struct WPack {
    const float* src[11];
    unsigned short* dst[11];
};
__global__ __launch_bounds__(256) void prep_weights(WPack p) {
    const int Ks[11] = {128, 128, 256, 256, 256, 256, 256, 256, 256, 256, 128};
    const int Ns[11] = {256, 256, 256, 256, 256, 256, 256, 256, 256, 128, 64};
    int seg = blockIdx.y;
    int K = Ks[seg], N = Ns[seg];
    int idx = blockIdx.x * 256 + threadIdx.x;
    if (idx >= K * N) return;
    int k = idx / N, n = idx % N;
    p.dst[seg][(size_t)n * K + k] = f2bf(p.src[seg][idx]);
}

// ---------------- bf16 MFMA GEMM (global_load_lds staging) ----------------
template <int BN_T, int OUT_MODE, int RELU, int BIAS, int DUAL>
__global__ __launch_bounds__(256) void gemm_mfma(const unsigned short* __restrict__ A, int lda,
                                                 const unsigned short* __restrict__ Wt,
                                                 const float* __restrict__ bias,
                                                 void* __restrict__ Cout, int ldc,
                                                 int M, int K,
                                                 const unsigned short* __restrict__ A2,
                                                 const unsigned short* __restrict__ Wt2) {
    constexpr int MI = (BN_T == 128) ? 4 : 2;
    constexpr int NI = 4;
    __shared__ __align__(16) short As[128 * 32];
    __shared__ __align__(16) short Bs[BN_T * 32];

    const int tid = threadIdx.x;
    const int l = tid & 63;
    const int wv = tid >> 6;
    const int wrow = (BN_T == 128) ? (wv >> 1) * 64 : wv * 32;
    const int wcol = (BN_T == 128) ? (wv & 1) * 64 : 0;
    const int bm = blockIdx.x * 128;
    int bn, coloff;
    const unsigned short* Ause;
    const unsigned short* Wuse;
    if (DUAL) {
        int half_ = blockIdx.y >> 1;
        bn = (blockIdx.y & 1) * BN_T;
        coloff = half_ * 256;
        Ause = half_ ? A2 : A;
        Wuse = half_ ? Wt2 : Wt;
    } else {
        bn = blockIdx.y * BN_T;
        coloff = 0;
        Ause = A;
        Wuse = Wt;
    }
    const int rsub = l >> 2;
    const int gl = l & 3;

    f32x4 acc[MI][NI] = {};

    for (int k0 = 0; k0 < K; k0 += 32) {
#pragma unroll
        for (int i = 0; i < 2; i++) {
            int lr = wv * 32 + i * 16 + rsub;
            int gr = bm + lr;
            if (gr >= M) gr = M - 1;
            int gsrc = gl ^ ((lr >> 1) & 3);
            gload_lds16(&Ause[(size_t)gr * lda + k0 + gsrc * 8],
                        &As[(wv * 32 + i * 16) * 32]);
        }
#pragma unroll
        for (int i = 0; i < BN_T / 64; i++) {
            int base = (BN_T == 128) ? (wv * 32 + i * 16) : (wv * 16);
            int lr = base + rsub;
            int gsrc = gl ^ ((lr >> 1) & 3);
            gload_lds16(&Wuse[(size_t)(bn + lr) * K + k0 + gsrc * 8],
                        &Bs[base * 32]);
        }
        __syncthreads();

        s16x8 af[MI], bfr[NI];
        const int q = l >> 4;
#pragma unroll
        for (int mi = 0; mi < MI; mi++) {
            int r = wrow + mi * 16 + (l & 15);
            af[mi] = *(const s16x8*)(&As[r * 32 + ((q ^ ((r >> 1) & 3)) << 3)]);
        }
#pragma unroll
        for (int ni = 0; ni < NI; ni++) {
            int r = wcol + ni * 16 + (l & 15);
            bfr[ni] = *(const s16x8*)(&Bs[r * 32 + ((q ^ ((r >> 1) & 3)) << 3)]);
        }
#pragma unroll
        for (int mi = 0; mi < MI; mi++)
#pragma unroll
            for (int ni = 0; ni < NI; ni++)
                acc[mi][ni] = __builtin_amdgcn_mfma_f32_16x16x32_bf16(af[mi], bfr[ni],
                                                                      acc[mi][ni], 0, 0, 0);
        __syncthreads();
    }

#pragma unroll
    for (int mi = 0; mi < MI; mi++) {
#pragma unroll
        for (int ni = 0; ni < NI; ni++) {
            int colB = coloff + bn + wcol + ni * 16 + (l & 15);
            float bv = BIAS ? bias[colB] : 0.0f;
#pragma unroll
            for (int r = 0; r < 4; r++) {
                int row = bm + wrow + mi * 16 + (l >> 4) * 4 + r;
                if (row < M) {
                    float v = acc[mi][ni][r] + bv;
                    if (RELU) v = fmaxf(v, 0.0f);
                    if (OUT_MODE == 1)
                        ((unsigned short*)Cout)[(size_t)row * ldc + colB] = f2bf(v);
                    else
                        ((float*)Cout)[(size_t)row * ldc + colB] = v;
                }
            }
        }
    }
}

// ---------------- fused edge MLP megakernel (128 edges, 512 threads) ----------------
__global__ __launch_bounds__(512, 4) void edge_mlp_fused(
    const unsigned short* __restrict__ PQ, const int2* __restrict__ pk,
    const int* __restrict__ edstA, const int* __restrict__ eorigA,
    const float* __restrict__ ea, const float* __restrict__ Wc1e,
    const float* __restrict__ bc1,
    const unsigned short* __restrict__ Wc2t, const float* __restrict__ bc2,
    const unsigned short* __restrict__ Wc3t, const float* __restrict__ bc3,
    const unsigned short* __restrict__ Wc4t, const float* __restrict__ bc4,
    const float* __restrict__ Wc5, const float* __restrict__ bc5,
    float* __restrict__ out) {
    __shared__ __align__(16) short At[EPB * 256];  // 64KB, swizzled [row][ch]
    __shared__ __align__(16) short Bs[256 * 32];   // 16KB weight staging

    const int tid = threadIdx.x;
    const int l = tid & 63;
    const int wv = tid >> 6;           // 0..7
    const int p0 = blockIdx.x * EPB;
    const int lm = l & 15;
    const int q = l >> 4;
    const int rsub = l >> 2;
    const int gl = l & 3;

    // ---- phase 0: gather + edge layer 1 -> At (row=edge, ch=0..255) ----
    {
        const int c0 = l * 4;
        float bi0 = bc1[c0], bi1 = bc1[c0 + 1], bi2 = bc1[c0 + 2], bi3 = bc1[c0 + 3];
        float4 w8[8];
#pragma unroll
        for (int jj = 0; jj < 8; jj++) w8[jj] = *(const float4*)(&Wc1e[jj * 256 + c0]);
        const int g = l >> 1;
        const int sub = (l & 1) * 4;
#pragma unroll 4
        for (int i = 0; i < 16; i++) {
            int row = wv * 16 + i;
            int p = p0 + row;
            int s = pk[p].x;
            int d = edstA[p];
            int eo = eorigA[p];
            union { int2 v; unsigned short u[4]; } Pu, Qu;
            Pu.v = *(const int2*)(&PQ[(size_t)s * 512 + c0]);
            Qu.v = *(const int2*)(&PQ[(size_t)d * 512 + 256 + c0]);
            float v0 = bf2f(Pu.u[0]) + bf2f(Qu.u[0]) + bi0;
            float v1 = bf2f(Pu.u[1]) + bf2f(Qu.u[1]) + bi1;
            float v2 = bf2f(Pu.u[2]) + bf2f(Qu.u[2]) + bi2;
            float v3 = bf2f(Pu.u[3]) + bf2f(Qu.u[3]) + bi3;
#pragma unroll
            for (int jj = 0; jj < 8; jj++) {
                float av = ea[(size_t)eo * 8 + jj];
                v0 = fmaf(av, w8[jj].x, v0);
                v1 = fmaf(av, w8[jj].y, v1);
                v2 = fmaf(av, w8[jj].z, v2);
                v3 = fmaf(av, w8[jj].w, v3);
            }
            unsigned short o0 = f2bf(fmaxf(v0, 0.0f)), o1 = f2bf(fmaxf(v1, 0.0f));
            unsigned short o2 = f2bf(fmaxf(v2, 0.0f)), o3 = f2bf(fmaxf(v3, 0.0f));
            int off = row * 256 + ((g ^ (row & 7)) << 3) + sub;
            *(uint2*)(&At[off]) =
                make_uint2(((unsigned)o1 << 16) | o0, ((unsigned)o3 << 16) | o2);
        }
    }
    __syncthreads();

    // ---- GEMM1: [128x256] = relu(At @ Wc2t^T + bc2) -> At ----
    {
        const int wrow = (wv >> 2) * 64;   // 0,64
        const int wcol = (wv & 3) * 64;    // 0,64,128,192
        f32x4 acc[4][4] = {};
        for (int k0 = 0; k0 < 256; k0 += 32) {
#pragma unroll
            for (int i = 0; i < 2; i++) {
                int lr = wv * 32 + i * 16 + rsub;
                int gsrc = gl ^ ((lr >> 1) & 3);
                gload_lds16(&Wc2t[(size_t)lr * 256 + k0 + gsrc * 8],
                            &Bs[(wv * 32 + i * 16) * 32]);
            }
            __syncthreads();
            s16x8 af[4], bfr[4];
#pragma unroll
            for (int mi = 0; mi < 4; mi++) {
                int r = wrow + mi * 16 + lm;
                int G = (k0 >> 3) + q;
                af[mi] = *(const s16x8*)(&At[r * 256 + ((G ^ (r & 7)) << 3)]);
            }
#pragma unroll
            for (int ni = 0; ni < 4; ni++) {
                int rb = wcol + ni * 16 + lm;
                bfr[ni] = *(const s16x8*)(&Bs[rb * 32 + ((q ^ ((rb >> 1) & 3)) << 3)]);
            }
#pragma unroll
            for (int mi = 0; mi < 4; mi++)
#pragma unroll
                for (int ni = 0; ni < 4; ni++)
                    acc[mi][ni] = __builtin_amdgcn_mfma_f32_16x16x32_bf16(
                        af[mi], bfr[ni], acc[mi][ni], 0, 0, 0);
            __syncthreads();
        }
        // epilogue back into At (all reads complete after final barrier)
#pragma unroll
        for (int mi = 0; mi < 4; mi++) {
#pragma unroll
            for (int ni = 0; ni < 4; ni++) {
                int col = wcol + ni * 16 + lm;
                float bv = bc2[col];
#pragma unroll
                for (int r = 0; r < 4; r++) {
                    int row = wrow + mi * 16 + q * 4 + r;
                    At[row * 256 + (((col >> 3) ^ (row & 7)) << 3) + (col & 7)] =
                        (short)f2bf(fmaxf(acc[mi][ni][r] + bv, 0.0f));
                }
            }
        }
    }
    __syncthreads();

    // ---- GEMM2: [128x128] = relu(A2 @ Wc3t^T + bc3) -> At (stride 128) ----
    {
        const int wrow = (wv >> 1) * 32;   // 0,32,64,96
        const int wcol = (wv & 1) * 64;    // 0,64
        f32x4 acc[2][4] = {};
        for (int k0 = 0; k0 < 256; k0 += 32) {
            {
                int lr = wv * 16 + rsub;
                int gsrc = gl ^ ((lr >> 1) & 3);
                gload_lds16(&Wc3t[(size_t)lr * 256 + k0 + gsrc * 8],
                            &Bs[(wv * 16) * 32]);
            }
            __syncthreads();
            s16x8 af[2], bfr[4];
#pragma unroll
            for (int mi = 0; mi < 2; mi++) {
                int r = wrow + mi * 16 + lm;
                int G = (k0 >> 3) + q;
                af[mi] = *(const s16x8*)(&At[r * 256 + ((G ^ (r & 7)) << 3)]);
            }
#pragma unroll
            for (int ni = 0; ni < 4; ni++) {
                int rb = wcol + ni * 16 + lm;
                bfr[ni] = *(const s16x8*)(&Bs[rb * 32 + ((q ^ ((rb >> 1) & 3)) << 3)]);
            }
#pragma unroll
            for (int mi = 0; mi < 2; mi++)
#pragma unroll
                for (int ni = 0; ni < 4; ni++)
                    acc[mi][ni] = __builtin_amdgcn_mfma_f32_16x16x32_bf16(
                        af[mi], bfr[ni], acc[mi][ni], 0, 0, 0);
            __syncthreads();
        }
#pragma unroll
        for (int mi = 0; mi < 2; mi++) {
#pragma unroll
            for (int ni = 0; ni < 4; ni++) {
                int col = wcol + ni * 16 + lm;
                float bv = bc3[col];
#pragma unroll
                for (int r = 0; r < 4; r++) {
                    int row = wrow + mi * 16 + q * 4 + r;
                    At[row * 128 + (((col >> 3) ^ (row & 7)) << 3) + (col & 7)] =
                        (short)f2bf(fmaxf(acc[mi][ni][r] + bv, 0.0f));
                }
            }
        }
    }
    __syncthreads();

    // ---- GEMM3: [128x64] = A3 @ Wc4t^T, fused relu+bc4 then @Wc5 + bc5, scatter ----
    {
        const int wrow = wv * 16;
        f32x4 acc[4] = {};
        for (int k0 = 0; k0 < 128; k0 += 32) {
            if (wv < 4) {
                int lr = wv * 16 + rsub;
                int gsrc = gl ^ ((lr >> 1) & 3);
                gload_lds16(&Wc4t[(size_t)lr * 128 + k0 + gsrc * 8],
                            &Bs[(wv * 16) * 32]);
            }
            __syncthreads();
            s16x8 af, bfr[4];
            {
                int r = wrow + lm;
                int G = (k0 >> 3) + q;
                af = *(const s16x8*)(&At[r * 128 + ((G ^ (r & 7)) << 3)]);
            }
#pragma unroll
            for (int ni = 0; ni < 4; ni++) {
                int rb = ni * 16 + lm;
                bfr[ni] = *(const s16x8*)(&Bs[rb * 32 + ((q ^ ((rb >> 1) & 3)) << 3)]);
            }
#pragma unroll
            for (int ni = 0; ni < 4; ni++)
                acc[ni] = __builtin_amdgcn_mfma_f32_16x16x32_bf16(af, bfr[ni],
                                                                  acc[ni], 0, 0, 0);
            __syncthreads();
        }
#pragma unroll
        for (int r = 0; r < 4; r++) {
            float pa = 0.f, pb = 0.f;
#pragma unroll
            for (int ni = 0; ni < 4; ni++) {
                int col = ni * 16 + lm;
                float v = fmaxf(acc[ni][r] + bc4[col], 0.0f);
                pa = fmaf(v, Wc5[col * 2 + 0], pa);
                pb = fmaf(v, Wc5[col * 2 + 1], pb);
            }
#pragma unroll
            for (int o = 1; o < 16; o <<= 1) {
                pa += __shfl_xor(pa, o, 64);
                pb += __shfl_xor(pb, o, 64);
            }
            if (lm == 0) {
                int row = wrow + q * 4 + r;
                int eo = eorigA[p0 + row];
                out[(size_t)eo * 2 + 0] = pa + bc5[0];
                out[(size_t)eo * 2 + 1] = pb + bc5[1];
            }
        }
    }
}

// ---------------- GCN aggregation: 1 node/wave, bf16 out, fused BN-stat atomics ----
__global__ __launch_bounds__(256) void aggregate2(const unsigned short* __restrict__ hwb,
                                                  const float* __restrict__ isd,
                                                  const int* __restrict__ offsets,
                                                  const int2* __restrict__ pk,
                                                  const float* __restrict__ b1,
                                                  const float* __restrict__ b2,
                                                  unsigned short* __restrict__ hagg,
                                                  float* __restrict__ stats) {
    int wv = threadIdx.x >> 6, l = threadIdx.x & 63;
    int n = blockIdx.x * 4 + wv;
    int c0 = l * 8;
    float acc[8] = {};
    int e0 = offsets[n], e1 = offsets[n + 1];
    int k = e0;
    for (; k + 2 <= e1; k += 2) {
        int2 p0 = pk[k], p1 = pk[k + 1];
        union { int4 v; unsigned short u[8]; } U0, U1;
        U0.v = *(const int4*)(&hwb[(size_t)p0.x * 512 + c0]);
        U1.v = *(const int4*)(&hwb[(size_t)p1.x * 512 + c0]);
        float w0 = __int_as_float(p0.y), w1 = __int_as_float(p1.y);
#pragma unroll
        for (int j = 0; j < 8; j++)
            acc[j] = fmaf(w0, bf2f(U0.u[j]), fmaf(w1, bf2f(U1.u[j]), acc[j]));
    }
    if (k < e1) {
        int2 p0 = pk[k];
        union { int4 v; unsigned short u[8]; } U0;
        U0.v = *(const int4*)(&hwb[(size_t)p0.x * 512 + c0]);
        float w0 = __int_as_float(p0.y);
#pragma unroll
        for (int j = 0; j < 8; j++) acc[j] = fmaf(w0, bf2f(U0.u[j]), acc[j]);
    }
    float si = isd[n]; si *= si;
    union { int4 v; unsigned short u[8]; } U;
    U.v = *(const int4*)(&hwb[(size_t)n * 512 + c0]);
    const float* bp = (c0 < 256) ? (b1 + c0) : (b2 + (c0 - 256));
    unsigned short os[8];
#pragma unroll
    for (int j = 0; j < 8; j++) {
        acc[j] = fmaf(si, bf2f(U.u[j]), acc[j]) + bp[j];
        os[j] = f2bf(acc[j]);
    }
    int4 ov;
    ov.x = (int)(((unsigned)os[1] << 16) | os[0]);
    ov.y = (int)(((unsigned)os[3] << 16) | os[2]);
    ov.z = (int)(((unsigned)os[5] << 16) | os[4]);
    ov.w = (int)(((unsigned)os[7] << 16) | os[6]);
    *(int4*)(&hagg[(size_t)n * 512 + c0]) = ov;
    // fused BN stats (device-scope atomics, no barrier)
#pragma unroll
    for (int j = 0; j < 8; j++) {
        atomicAdd(&stats[c0 + j], acc[j]);
        atomicAdd(&stats[512 + c0 + j], acc[j] * acc[j]);
    }
}

// stats -> per-channel affine AB; also re-zeros stats for the next layer
__global__ __launch_bounds__(256) void bn_ab(const float* __restrict__ stats,
                                             const float* __restrict__ g,
                                             const float* __restrict__ be,
                                             float* __restrict__ AB,
                                             float* __restrict__ stats_mut) {
    int t = threadIdx.x;
#pragma unroll
    for (int h = 0; h < 2; h++) {
        int c = t + h * 256;
        float m = stats[c] * (1.0f / N_NODES);
        float var = stats[512 + c] * (1.0f / N_NODES) - m * m;
        float sc = g[c & 255] * rsqrtf(var + BN_EPS);
        AB[c] = sc;
        AB[512 + c] = be[c & 255] - m * sc;
        stats_mut[c] = 0.0f;
        stats_mut[512 + c] = 0.0f;
    }
}

// y = relu(x*A + B), bf16 in/out, 512-wide
__global__ __launch_bounds__(256) void bn_apply(const unsigned short* __restrict__ h,
                                                const float* __restrict__ AB,
                                                unsigned short* __restrict__ outp) {
    int i8 = blockIdx.x * blockDim.x + threadIdx.x;
    if (i8 >= N_NODES * 512 / 8) return;
    int c8 = (i8 & 63) * 8;
    union { int4 v; unsigned short u[8]; } U;
    U.v = *(const int4*)(&h[(size_t)i8 * 8]);
    unsigned short os[8];
#pragma unroll
    for (int j = 0; j < 8; j++) {
        int c = c8 + j;
        float y = fmaf(bf2f(U.u[j]), AB[c], AB[512 + c]);
        os[j] = f2bf(fmaxf(y, 0.0f));
    }
    int4 ov;
    ov.x = (int)(((unsigned)os[1] << 16) | os[0]);
    ov.y = (int)(((unsigned)os[3] << 16) | os[2]);
    ov.z = (int)(((unsigned)os[5] << 16) | os[4]);
    ov.w = (int)(((unsigned)os[7] << 16) | os[6]);
    *(int4*)(&outp[(size_t)i8 * 8]) = ov;
}

// final: hc = relu(bn(h1)) + relu(bn(h2)), bf16 out 256-wide
__global__ __launch_bounds__(256) void bn_apply_final(const unsigned short* __restrict__ h,
                                                      const float* __restrict__ AB,
                                                      unsigned short* __restrict__ hc) {
    int i8 = blockIdx.x * blockDim.x + threadIdx.x;
    if (i8 >= N_NODES * 256 / 8) return;
    int n = i8 >> 5;
    int c8 = (i8 & 31) * 8;
    union { int4 v; unsigned short u[8]; } U1, U2;
    U1.v = *(const int4*)(&h[(size_t)n * 512 + c8]);
    U2.v = *(const int4*)(&h[(size_t)n * 512 + 256 + c8]);
    unsigned short os[8];
#pragma unroll
    for (int j = 0; j < 8; j++) {
        int c = c8 + j;
        float y1 = fmaxf(fmaf(bf2f(U1.u[j]), AB[c], AB[512 + c]), 0.0f);
        int c2 = c + 256;
        float y2 = fmaxf(fmaf(bf2f(U2.u[j]), AB[c2], AB[512 + c2]), 0.0f);
        os[j] = f2bf(y1 + y2);
    }
    int4 ov;
    ov.x = (int)(((unsigned)os[1] << 16) | os[0]);
    ov.y = (int)(((unsigned)os[3] << 16) | os[2]);
    ov.z = (int)(((unsigned)os[5] << 16) | os[4]);
    ov.w = (int)(((unsigned)os[7] << 16) | os[6]);
    *(int4*)(&hc[(size_t)i8 * 8]) = ov;
}

// ---------------- launch ----------------
extern "C" void kernel_launch(void* const* d_in, const int* in_sizes, int n_in,
                              void* d_out, int out_size, void* d_ws, size_t ws_size,
                              hipStream_t stream) {
    const float* x   = (const float*)d_in[0];
    const int*   ei  = (const int*)d_in[1];
    const float* ea  = (const float*)d_in[2];
    const float* W11 = (const float*)d_in[3];
    const float* b11 = (const float*)d_in[4];
    const float* W12 = (const float*)d_in[5];
    const float* b12 = (const float*)d_in[6];
    const float* W13 = (const float*)d_in[7];
    const float* b13 = (const float*)d_in[8];
    const float* W21 = (const float*)d_in[9];
    const float* b21 = (const float*)d_in[10];
    const float* W22 = (const float*)d_in[11];
    const float* b22 = (const float*)d_in[12];
    const float* W23 = (const float*)d_in[13];
    const float* b23 = (const float*)d_in[14];
    const float* g1  = (const float*)d_in[15];
    const float* be1 = (const float*)d_in[16];
    const float* g2  = (const float*)d_in[17];
    const float* be2 = (const float*)d_in[18];
    const float* g3  = (const float*)d_in[19];
    const float* be3 = (const float*)d_in[20];
    const float* Wc1 = (const float*)d_in[21];
    const float* bc1 = (const float*)d_in[22];
    const float* Wc2 = (const float*)d_in[23];
    const float* bc2 = (const float*)d_in[24];
    const float* Wc3 = (const float*)d_in[25];
    const float* bc3 = (const float*)d_in[26];
    const float* Wc4 = (const float*)d_in[27];
    const float* bc4 = (const float*)d_in[28];
    const float* Wc5 = (const float*)d_in[29];
    const float* bc5 = (const float*)d_in[30];

    const int* src = ei;
    const int* dst = ei + N_EDGES;
    float* out = (float*)d_out;

    // ---- workspace carve ----
    char* w = (char*)d_ws;
    auto alloc = [&](size_t bytes) {
        char* p = w;
        w += (bytes + 255) & ~(size_t)255;
        return p;
    };
    float* isd     = (float*)alloc(N_NODES * 4);
    int2*  pk      = (int2*)alloc((size_t)N_EDGES * 8);
    int*   edstA   = (int*)alloc((size_t)N_EDGES * 4);
    int*   eorigA  = (int*)alloc((size_t)N_EDGES * 4);
    int*   counts  = (int*)alloc((N_NODES + 4) * 4);
    int*   offsets = (int*)alloc((N_NODES + 4) * 4);
    int*   bsum    = (int*)alloc(256 * 4);
    int*   boff    = (int*)alloc(256 * 4);
    float* stats   = (float*)alloc(1024 * 4);
    float* AB      = (float*)alloc(1024 * 4);
    unsigned short* W11t = (unsigned short*)alloc(256 * 128 * 2);
    unsigned short* W21t = (unsigned short*)alloc(256 * 128 * 2);
    unsigned short* W12t = (unsigned short*)alloc(256 * 256 * 2);
    unsigned short* W22t = (unsigned short*)alloc(256 * 256 * 2);
    unsigned short* W13t = (unsigned short*)alloc(256 * 256 * 2);
    unsigned short* W23t = (unsigned short*)alloc(256 * 256 * 2);
    unsigned short* WPQt = (unsigned short*)alloc(512 * 256 * 2);
    unsigned short* Wc2t = (unsigned short*)alloc(256 * 256 * 2);
    unsigned short* Wc3t = (unsigned short*)alloc(128 * 256 * 2);
    unsigned short* Wc4t = (unsigned short*)alloc(64 * 128 * 2);
    unsigned short* xb   = (unsigned short*)alloc((size_t)N_NODES * 128 * 2);
    unsigned short* hb   = (unsigned short*)alloc((size_t)N_NODES * 512 * 2);
    unsigned short* hwb  = (unsigned short*)alloc((size_t)N_NODES * 512 * 2);
    unsigned short* hagg = (unsigned short*)alloc((size_t)N_NODES * 512 * 2);
    unsigned short* hc   = (unsigned short*)alloc((size_t)N_NODES * 256 * 2);
    (void)ws_size;

    // ---- CSR build ----
    zero_i32<<<(N_NODES + 256) / 256, 256, 0, stream>>>(counts, N_NODES + 1);
    count_deg<<<(N_EDGES + 255) / 256, 256, 0, stream>>>(dst, counts);
    isd_kernel<<<(N_NODES + 255) / 256, 256, 0, stream>>>(counts, isd);
    scan_reduce<<<NB_SCAN, 256, 0, stream>>>(counts, bsum);
    scan_tops<<<1, 256, 0, stream>>>(bsum, boff, NB_SCAN, offsets + N_NODES);
    scan_final<<<NB_SCAN, 256, 0, stream>>>(counts, boff, offsets);
    zero_i32<<<(N_NODES + 255) / 256, 256, 0, stream>>>(counts, N_NODES);
    fill_csr<<<(N_EDGES + 255) / 256, 256, 0, stream>>>(src, dst, isd, offsets, counts,
                                                        pk, edstA, eorigA);

    // ---- preconvert (x -> bf16; all 11 weight transposes in ONE dispatch) ----
    conv_f32_bf16<<<(N_NODES * 128 / 4 + 255) / 256, 256, 0, stream>>>(x, xb,
                                                                        N_NODES * 128 / 4);
    WPack wp;
    wp.src[0] = W11; wp.dst[0] = W11t;
    wp.src[1] = W21; wp.dst[1] = W21t;
    wp.src[2] = W12; wp.dst[2] = W12t;
    wp.src[3] = W22; wp.dst[3] = W22t;
    wp.src[4] = W13; wp.dst[4] = W13t;
    wp.src[5] = W23; wp.dst[5] = W23t;
    wp.src[6] = Wc1; wp.dst[6] = WPQt;
    wp.src[7] = Wc1 + 256 * 256; wp.dst[7] = WPQt + 256 * 256;
    wp.src[8] = Wc2; wp.dst[8] = Wc2t;
    wp.src[9] = Wc3; wp.dst[9] = Wc3t;
    wp.src[10] = Wc4; wp.dst[10] = Wc4t;
    prep_weights<<<dim3(256, 11), 256, 0, stream>>>(wp);

    // stats zero (post-poison init; bn_ab re-zeros between layers)
    zero_f32<<<4, 256, 0, stream>>>(stats, 1024);

    // ---- 3 GCN layers (dual-branch GEMM in one dispatch) ----
    const unsigned short* Wat[3] = {W11t, W12t, W13t};
    const unsigned short* Wbt[3] = {W21t, W22t, W23t};
    const float* ba[3] = {b11, b12, b13};
    const float* bb[3] = {b21, b22, b23};
    const float* gs[3] = {g1, g2, g3};
    const float* bes[3] = {be1, be2, be3};

    int gx_n = (N_NODES + 127) / 128;  // 391
    for (int l = 0; l < 3; l++) {
        if (l == 0) {
            gemm_mfma<128, 1, 0, 0, 1><<<dim3(gx_n, 4), 256, 0, stream>>>(
                xb, 128, Wat[0], nullptr, hwb, 512, N_NODES, 128, xb, Wbt[0]);
        } else {
            gemm_mfma<128, 1, 0, 0, 1><<<dim3(gx_n, 4), 256, 0, stream>>>(
                hb, 512, Wat[l], nullptr, hwb, 512, N_NODES, 256, hb + 256, Wbt[l]);
        }
        aggregate2<<<N_NODES / 4, 256, 0, stream>>>(hwb, isd, offsets, pk,
                                                    ba[l], bb[l], hagg, stats);
        bn_ab<<<1, 256, 0, stream>>>(stats, gs[l], bes[l], AB, stats);
        if (l < 2) {
            bn_apply<<<(N_NODES * 512 / 8 + 255) / 256, 256, 0, stream>>>(hagg, AB, hb);
        } else {
            bn_apply_final<<<(N_NODES * 256 / 8 + 255) / 256, 256, 0, stream>>>(hagg, AB, hc);
        }
    }

    // ---- PQ = hc @ [Wc1_P | Wc1_Q] -> hwb [N][512] bf16 ----
    gemm_mfma<128, 1, 0, 0, 0><<<dim3(gx_n, 4), 256, 0, stream>>>(hc, 256, WPQt, nullptr,
                                                                  hwb, 512, N_NODES, 256,
                                                                  nullptr, nullptr);

    // ---- fused edge MLP: one dispatch, all 400K edges ----
    edge_mlp_fused<<<N_EDGES / EPB, 512, 0, stream>>>(
        hwb, pk, edstA, eorigA, ea, Wc1 + 512 * 256, bc1,
        Wc2t, bc2, Wc3t, bc3, Wc4t, bc4, Wc5, bc5, out);
}

// Round 10
// 744.490 us; speedup vs baseline: 39.3646x; 39.3646x over previous
//
#include <hip/hip_runtime.h>

#define N_NODES 50000
#define N_EDGES 400000
#define EPB     128          // edges per block in fused edge MLP
#define NB_SCAN 196
#define BN_EPS  1e-5f
#define STAT_BLOCKS 128

typedef __attribute__((ext_vector_type(8))) short s16x8;
typedef __attribute__((ext_vector_type(4))) float f32x4;

__device__ __forceinline__ unsigned short f2bf(float x) {
    unsigned u = __float_as_uint(x);
    return (unsigned short)((u + 0x7fffu + ((u >> 16) & 1u)) >> 16);
}
__device__ __forceinline__ float bf2f(unsigned short b) {
    return __uint_as_float(((unsigned)b) << 16);
}

// direct global->LDS 16B load (linear LDS dest = wave base + lane*16)
__device__ __forceinline__ void gload_lds16(const void* g, void* lds) {
    auto gp = reinterpret_cast<const __attribute__((address_space(1))) unsigned int*>(
        reinterpret_cast<uintptr_t>(g));
    auto lp = reinterpret_cast<__attribute__((address_space(3))) unsigned int*>(
        reinterpret_cast<uintptr_t>(lds));
    __builtin_amdgcn_global_load_lds(gp, lp, 16, 0, 0);
}

// ---------------- utility ----------------
__global__ void zero_i32(int* p, int n) {
    int i = blockIdx.x * blockDim.x + threadIdx.x;
    if (i < n) p[i] = 0;
}
__global__ void zero_f32(float* p, int n) {
    int i = blockIdx.x * blockDim.x + threadIdx.x;
    if (i < n) p[i] = 0.0f;
}
__global__ void count_deg(const int* __restrict__ dst, int* __restrict__ counts) {
    int e = blockIdx.x * blockDim.x + threadIdx.x;
    if (e < N_EDGES) atomicAdd(&counts[dst[e]], 1);
}
__global__ void isd_kernel(const int* __restrict__ counts, float* __restrict__ isd) {
    int i = blockIdx.x * blockDim.x + threadIdx.x;
    if (i < N_NODES) isd[i] = rsqrtf(1.0f + (float)counts[i]);
}

// ---------------- 3-phase scan ----------------
__global__ __launch_bounds__(256) void scan_reduce(const int* __restrict__ counts,
                                                   int* __restrict__ bsum) {
    __shared__ int sh[256];
    int t = threadIdx.x, b = blockIdx.x;
    int i = b * 256 + t;
    sh[t] = (i < N_NODES) ? counts[i] : 0;
    __syncthreads();
    for (int o = 128; o > 0; o >>= 1) {
        if (t < o) sh[t] += sh[t + o];
        __syncthreads();
    }
    if (t == 0) bsum[b] = sh[0];
}
__global__ __launch_bounds__(256) void scan_tops(const int* __restrict__ bsum,
                                                 int* __restrict__ boff, int nb,
                                                 int* __restrict__ total_out) {
    __shared__ int sh[256];
    int t = threadIdx.x;
    int v = (t < nb) ? bsum[t] : 0;
    sh[t] = v;
    __syncthreads();
    for (int o = 1; o < 256; o <<= 1) {
        int a = (t >= o) ? sh[t - o] : 0;
        __syncthreads();
        sh[t] += a;
        __syncthreads();
    }
    if (t < nb) boff[t] = sh[t] - v;
    if (t == 255) *total_out = sh[255];
}
__global__ __launch_bounds__(256) void scan_final(const int* __restrict__ counts,
                                                  const int* __restrict__ boff,
                                                  int* __restrict__ offsets) {
    __shared__ int sh[256];
    int t = threadIdx.x, b = blockIdx.x;
    int i = b * 256 + t;
    int v = (i < N_NODES) ? counts[i] : 0;
    sh[t] = v;
    __syncthreads();
    for (int o = 1; o < 256; o <<= 1) {
        int a = (t >= o) ? sh[t - o] : 0;
        __syncthreads();
        sh[t] += a;
        __syncthreads();
    }
    if (i < N_NODES) offsets[i] = boff[b] + sh[t] - v;
}

// packed CSR entry: (src, norm) as int2; also dst and orig-edge-id per CSR slot
__global__ void fill_csr(const int* __restrict__ src, const int* __restrict__ dst,
                         const float* __restrict__ isd, const int* __restrict__ offsets,
                         int* __restrict__ cursor, int2* __restrict__ pk,
                         int* __restrict__ edstA, int* __restrict__ eorigA) {
    int e = blockIdx.x * blockDim.x + threadIdx.x;
    if (e >= N_EDGES) return;
    int s = src[e], d = dst[e];
    int pos = offsets[d] + atomicAdd(&cursor[d], 1);
    pk[pos] = make_int2(s, __float_as_int(isd[s] * isd[d]));
    edstA[pos] = d;
    eorigA[pos] = e;
}

// ---------------- conversions ----------------
__global__ void conv_f32_bf16(const float* __restrict__ in, unsigned short* __restrict__ out,
                              int n4) {
    int i = blockIdx.x * blockDim.x + threadIdx.x;
    if (i >= n4) return;
    float4 v = ((const float4*)in)[i];
    unsigned short o0 = f2bf(v.x), o1 = f2bf(v.y), o2 = f2bf(v.z), o3 = f2bf(v.w);
    ((uint2*)out)[i] = make_uint2(((unsigned)o1 << 16) | o0, ((unsigned)o3 << 16) | o2);
}

// all 11 weight transposes (fp32 [K][N] -> bf16 [N][K]) in one dispatch
struct WPack {
    const float* src[11];
    unsigned short* dst[11];
};
__global__ __launch_bounds__(256) void prep_weights(WPack p) {
    const int Ks[11] = {128, 128, 256, 256, 256, 256, 256, 256, 256, 256, 128};
    const int Ns[11] = {256, 256, 256, 256, 256, 256, 256, 256, 256, 128, 64};
    int seg = blockIdx.y;
    int K = Ks[seg], N = Ns[seg];
    int idx = blockIdx.x * 256 + threadIdx.x;
    if (idx >= K * N) return;
    int k = idx / N, n = idx % N;
    p.dst[seg][(size_t)n * K + k] = f2bf(p.src[seg][idx]);
}

// ---------------- bf16 MFMA GEMM (global_load_lds staging) ----------------
template <int BN_T, int OUT_MODE, int RELU, int BIAS, int DUAL>
__global__ __launch_bounds__(256) void gemm_mfma(const unsigned short* __restrict__ A, int lda,
                                                 const unsigned short* __restrict__ Wt,
                                                 const float* __restrict__ bias,
                                                 void* __restrict__ Cout, int ldc,
                                                 int M, int K,
                                                 const unsigned short* __restrict__ A2,
                                                 const unsigned short* __restrict__ Wt2) {
    constexpr int MI = (BN_T == 128) ? 4 : 2;
    constexpr int NI = 4;
    __shared__ __align__(16) short As[128 * 32];
    __shared__ __align__(16) short Bs[BN_T * 32];

    const int tid = threadIdx.x;
    const int l = tid & 63;
    const int wv = tid >> 6;
    const int wrow = (BN_T == 128) ? (wv >> 1) * 64 : wv * 32;
    const int wcol = (BN_T == 128) ? (wv & 1) * 64 : 0;
    const int bm = blockIdx.x * 128;
    int bn, coloff;
    const unsigned short* Ause;
    const unsigned short* Wuse;
    if (DUAL) {
        int half_ = blockIdx.y >> 1;
        bn = (blockIdx.y & 1) * BN_T;
        coloff = half_ * 256;
        Ause = half_ ? A2 : A;
        Wuse = half_ ? Wt2 : Wt;
    } else {
        bn = blockIdx.y * BN_T;
        coloff = 0;
        Ause = A;
        Wuse = Wt;
    }
    const int rsub = l >> 2;
    const int gl = l & 3;

    f32x4 acc[MI][NI] = {};

    for (int k0 = 0; k0 < K; k0 += 32) {
#pragma unroll
        for (int i = 0; i < 2; i++) {
            int lr = wv * 32 + i * 16 + rsub;
            int gr = bm + lr;
            if (gr >= M) gr = M - 1;
            int gsrc = gl ^ ((lr >> 1) & 3);
            gload_lds16(&Ause[(size_t)gr * lda + k0 + gsrc * 8],
                        &As[(wv * 32 + i * 16) * 32]);
        }
#pragma unroll
        for (int i = 0; i < BN_T / 64; i++) {
            int base = (BN_T == 128) ? (wv * 32 + i * 16) : (wv * 16);
            int lr = base + rsub;
            int gsrc = gl ^ ((lr >> 1) & 3);
            gload_lds16(&Wuse[(size_t)(bn + lr) * K + k0 + gsrc * 8],
                        &Bs[base * 32]);
        }
        __syncthreads();

        s16x8 af[MI], bfr[NI];
        const int q = l >> 4;
#pragma unroll
        for (int mi = 0; mi < MI; mi++) {
            int r = wrow + mi * 16 + (l & 15);
            af[mi] = *(const s16x8*)(&As[r * 32 + ((q ^ ((r >> 1) & 3)) << 3)]);
        }
#pragma unroll
        for (int ni = 0; ni < NI; ni++) {
            int r = wcol + ni * 16 + (l & 15);
            bfr[ni] = *(const s16x8*)(&Bs[r * 32 + ((q ^ ((r >> 1) & 3)) << 3)]);
        }
#pragma unroll
        for (int mi = 0; mi < MI; mi++)
#pragma unroll
            for (int ni = 0; ni < NI; ni++)
                acc[mi][ni] = __builtin_amdgcn_mfma_f32_16x16x32_bf16(af[mi], bfr[ni],
                                                                      acc[mi][ni], 0, 0, 0);
        __syncthreads();
    }

#pragma unroll
    for (int mi = 0; mi < MI; mi++) {
#pragma unroll
        for (int ni = 0; ni < NI; ni++) {
            int colB = coloff + bn + wcol + ni * 16 + (l & 15);
            float bv = BIAS ? bias[colB] : 0.0f;
#pragma unroll
            for (int r = 0; r < 4; r++) {
                int row = bm + wrow + mi * 16 + (l >> 4) * 4 + r;
                if (row < M) {
                    float v = acc[mi][ni][r] + bv;
                    if (RELU) v = fmaxf(v, 0.0f);
                    if (OUT_MODE == 1)
                        ((unsigned short*)Cout)[(size_t)row * ldc + colB] = f2bf(v);
                    else
                        ((float*)Cout)[(size_t)row * ldc + colB] = v;
                }
            }
        }
    }
}

// ---------------- fused edge MLP megakernel (128 edges, 512 threads) ----------------
__global__ __launch_bounds__(512, 4) void edge_mlp_fused(
    const unsigned short* __restrict__ PQ, const int2* __restrict__ pk,
    const int* __restrict__ edstA, const int* __restrict__ eorigA,
    const float* __restrict__ ea, const float* __restrict__ Wc1e,
    const float* __restrict__ bc1,
    const unsigned short* __restrict__ Wc2t, const float* __restrict__ bc2,
    const unsigned short* __restrict__ Wc3t, const float* __restrict__ bc3,
    const unsigned short* __restrict__ Wc4t, const float* __restrict__ bc4,
    const float* __restrict__ Wc5, const float* __restrict__ bc5,
    float* __restrict__ out) {
    __shared__ __align__(16) short At[EPB * 256];  // 64KB, swizzled [row][ch]
    __shared__ __align__(16) short Bs[256 * 32];   // 16KB weight staging

    const int tid = threadIdx.x;
    const int l = tid & 63;
    const int wv = tid >> 6;           // 0..7
    const int p0 = blockIdx.x * EPB;
    const int lm = l & 15;
    const int q = l >> 4;
    const int rsub = l >> 2;
    const int gl = l & 3;

    // ---- phase 0: gather + edge layer 1 -> At (row=edge, ch=0..255) ----
    {
        const int c0 = l * 4;
        float bi0 = bc1[c0], bi1 = bc1[c0 + 1], bi2 = bc1[c0 + 2], bi3 = bc1[c0 + 3];
        float4 w8[8];
#pragma unroll
        for (int jj = 0; jj < 8; jj++) w8[jj] = *(const float4*)(&Wc1e[jj * 256 + c0]);
        const int g = l >> 1;
        const int sub = (l & 1) * 4;
#pragma unroll 4
        for (int i = 0; i < 16; i++) {
            int row = wv * 16 + i;
            int p = p0 + row;
            int s = pk[p].x;
            int d = edstA[p];
            int eo = eorigA[p];
            union { int2 v; unsigned short u[4]; } Pu, Qu;
            Pu.v = *(const int2*)(&PQ[(size_t)s * 512 + c0]);
            Qu.v = *(const int2*)(&PQ[(size_t)d * 512 + 256 + c0]);
            float v0 = bf2f(Pu.u[0]) + bf2f(Qu.u[0]) + bi0;
            float v1 = bf2f(Pu.u[1]) + bf2f(Qu.u[1]) + bi1;
            float v2 = bf2f(Pu.u[2]) + bf2f(Qu.u[2]) + bi2;
            float v3 = bf2f(Pu.u[3]) + bf2f(Qu.u[3]) + bi3;
#pragma unroll
            for (int jj = 0; jj < 8; jj++) {
                float av = ea[(size_t)eo * 8 + jj];
                v0 = fmaf(av, w8[jj].x, v0);
                v1 = fmaf(av, w8[jj].y, v1);
                v2 = fmaf(av, w8[jj].z, v2);
                v3 = fmaf(av, w8[jj].w, v3);
            }
            unsigned short o0 = f2bf(fmaxf(v0, 0.0f)), o1 = f2bf(fmaxf(v1, 0.0f));
            unsigned short o2 = f2bf(fmaxf(v2, 0.0f)), o3 = f2bf(fmaxf(v3, 0.0f));
            int off = row * 256 + ((g ^ (row & 7)) << 3) + sub;
            *(uint2*)(&At[off]) =
                make_uint2(((unsigned)o1 << 16) | o0, ((unsigned)o3 << 16) | o2);
        }
    }
    __syncthreads();

    // ---- GEMM1: [128x256] = relu(At @ Wc2t^T + bc2) -> At ----
    {
        const int wrow = (wv >> 2) * 64;   // 0,64
        const int wcol = (wv & 3) * 64;    // 0,64,128,192
        f32x4 acc[4][4] = {};
        for (int k0 = 0; k0 < 256; k0 += 32) {
#pragma unroll
            for (int i = 0; i < 2; i++) {
                int lr = wv * 32 + i * 16 + rsub;
                int gsrc = gl ^ ((lr >> 1) & 3);
                gload_lds16(&Wc2t[(size_t)lr * 256 + k0 + gsrc * 8],
                            &Bs[(wv * 32 + i * 16) * 32]);
            }
            __syncthreads();
            s16x8 af[4], bfr[4];
#pragma unroll
            for (int mi = 0; mi < 4; mi++) {
                int r = wrow + mi * 16 + lm;
                int G = (k0 >> 3) + q;
                af[mi] = *(const s16x8*)(&At[r * 256 + ((G ^ (r & 7)) << 3)]);
            }
#pragma unroll
            for (int ni = 0; ni < 4; ni++) {
                int rb = wcol + ni * 16 + lm;
                bfr[ni] = *(const s16x8*)(&Bs[rb * 32 + ((q ^ ((rb >> 1) & 3)) << 3)]);
            }
#pragma unroll
            for (int mi = 0; mi < 4; mi++)
#pragma unroll
                for (int ni = 0; ni < 4; ni++)
                    acc[mi][ni] = __builtin_amdgcn_mfma_f32_16x16x32_bf16(
                        af[mi], bfr[ni], acc[mi][ni], 0, 0, 0);
            __syncthreads();
        }
        // epilogue back into At (all reads complete after final barrier)
#pragma unroll
        for (int mi = 0; mi < 4; mi++) {
#pragma unroll
            for (int ni = 0; ni < 4; ni++) {
                int col = wcol + ni * 16 + lm;
                float bv = bc2[col];
#pragma unroll
                for (int r = 0; r < 4; r++) {
                    int row = wrow + mi * 16 + q * 4 + r;
                    At[row * 256 + (((col >> 3) ^ (row & 7)) << 3) + (col & 7)] =
                        (short)f2bf(fmaxf(acc[mi][ni][r] + bv, 0.0f));
                }
            }
        }
    }
    __syncthreads();

    // ---- GEMM2: [128x128] = relu(A2 @ Wc3t^T + bc3) -> At (stride 128) ----
    {
        const int wrow = (wv >> 1) * 32;   // 0,32,64,96
        const int wcol = (wv & 1) * 64;    // 0,64
        f32x4 acc[2][4] = {};
        for (int k0 = 0; k0 < 256; k0 += 32) {
            {
                int lr = wv * 16 + rsub;
                int gsrc = gl ^ ((lr >> 1) & 3);
                gload_lds16(&Wc3t[(size_t)lr * 256 + k0 + gsrc * 8],
                            &Bs[(wv * 16) * 32]);
            }
            __syncthreads();
            s16x8 af[2], bfr[4];
#pragma unroll
            for (int mi = 0; mi < 2; mi++) {
                int r = wrow + mi * 16 + lm;
                int G = (k0 >> 3) + q;
                af[mi] = *(const s16x8*)(&At[r * 256 + ((G ^ (r & 7)) << 3)]);
            }
#pragma unroll
            for (int ni = 0; ni < 4; ni++) {
                int rb = wcol + ni * 16 + lm;
                bfr[ni] = *(const s16x8*)(&Bs[rb * 32 + ((q ^ ((rb >> 1) & 3)) << 3)]);
            }
#pragma unroll
            for (int mi = 0; mi < 2; mi++)
#pragma unroll
                for (int ni = 0; ni < 4; ni++)
                    acc[mi][ni] = __builtin_amdgcn_mfma_f32_16x16x32_bf16(
                        af[mi], bfr[ni], acc[mi][ni], 0, 0, 0);
            __syncthreads();
        }
#pragma unroll
        for (int mi = 0; mi < 2; mi++) {
#pragma unroll
            for (int ni = 0; ni < 4; ni++) {
                int col = wcol + ni * 16 + lm;
                float bv = bc3[col];
#pragma unroll
                for (int r = 0; r < 4; r++) {
                    int row = wrow + mi * 16 + q * 4 + r;
                    At[row * 128 + (((col >> 3) ^ (row & 7)) << 3) + (col & 7)] =
                        (short)f2bf(fmaxf(acc[mi][ni][r] + bv, 0.0f));
                }
            }
        }
    }
    __syncthreads();

    // ---- GEMM3: [128x64] = A3 @ Wc4t^T, fused relu+bc4 then @Wc5 + bc5, scatter ----
    {
        const int wrow = wv * 16;
        f32x4 acc[4] = {};
        for (int k0 = 0; k0 < 128; k0 += 32) {
            if (wv < 4) {
                int lr = wv * 16 + rsub;
                int gsrc = gl ^ ((lr >> 1) & 3);
                gload_lds16(&Wc4t[(size_t)lr * 128 + k0 + gsrc * 8],
                            &Bs[(wv * 16) * 32]);
            }
            __syncthreads();
            s16x8 af, bfr[4];
            {
                int r = wrow + lm;
                int G = (k0 >> 3) + q;
                af = *(const s16x8*)(&At[r * 128 + ((G ^ (r & 7)) << 3)]);
            }
#pragma unroll
            for (int ni = 0; ni < 4; ni++) {
                int rb = ni * 16 + lm;
                bfr[ni] = *(const s16x8*)(&Bs[rb * 32 + ((q ^ ((rb >> 1) & 3)) << 3)]);
            }
#pragma unroll
            for (int ni = 0; ni < 4; ni++)
                acc[ni] = __builtin_amdgcn_mfma_f32_16x16x32_bf16(af, bfr[ni],
                                                                  acc[ni], 0, 0, 0);
            __syncthreads();
        }
#pragma unroll
        for (int r = 0; r < 4; r++) {
            float pa = 0.f, pb = 0.f;
#pragma unroll
            for (int ni = 0; ni < 4; ni++) {
                int col = ni * 16 + lm;
                float v = fmaxf(acc[ni][r] + bc4[col], 0.0f);
                pa = fmaf(v, Wc5[col * 2 + 0], pa);
                pb = fmaf(v, Wc5[col * 2 + 1], pb);
            }
#pragma unroll
            for (int o = 1; o < 16; o <<= 1) {
                pa += __shfl_xor(pa, o, 64);
                pb += __shfl_xor(pb, o, 64);
            }
            if (lm == 0) {
                int row = wrow + q * 4 + r;
                int eo = eorigA[p0 + row];
                out[(size_t)eo * 2 + 0] = pa + bc5[0];
                out[(size_t)eo * 2 + 1] = pb + bc5[1];
            }
        }
    }
}

// ---------------- GCN aggregation: 1 node/wave, packed pairs, bf16 out ----------------
__global__ __launch_bounds__(256) void aggregate2(const unsigned short* __restrict__ hwb,
                                                  const float* __restrict__ isd,
                                                  const int* __restrict__ offsets,
                                                  const int2* __restrict__ pk,
                                                  const float* __restrict__ b1,
                                                  const float* __restrict__ b2,
                                                  unsigned short* __restrict__ hagg) {
    int wv = threadIdx.x >> 6, l = threadIdx.x & 63;
    int n = blockIdx.x * 4 + wv;
    int c0 = l * 8;
    float acc[8] = {};
    int e0 = offsets[n], e1 = offsets[n + 1];
    int k = e0;
    for (; k + 2 <= e1; k += 2) {
        int2 p0 = pk[k], p1 = pk[k + 1];
        union { int4 v; unsigned short u[8]; } U0, U1;
        U0.v = *(const int4*)(&hwb[(size_t)p0.x * 512 + c0]);
        U1.v = *(const int4*)(&hwb[(size_t)p1.x * 512 + c0]);
        float w0 = __int_as_float(p0.y), w1 = __int_as_float(p1.y);
#pragma unroll
        for (int j = 0; j < 8; j++)
            acc[j] = fmaf(w0, bf2f(U0.u[j]), fmaf(w1, bf2f(U1.u[j]), acc[j]));
    }
    if (k < e1) {
        int2 p0 = pk[k];
        union { int4 v; unsigned short u[8]; } U0;
        U0.v = *(const int4*)(&hwb[(size_t)p0.x * 512 + c0]);
        float w0 = __int_as_float(p0.y);
#pragma unroll
        for (int j = 0; j < 8; j++) acc[j] = fmaf(w0, bf2f(U0.u[j]), acc[j]);
    }
    float si = isd[n]; si *= si;
    union { int4 v; unsigned short u[8]; } U;
    U.v = *(const int4*)(&hwb[(size_t)n * 512 + c0]);
    const float* bp = (c0 < 256) ? (b1 + c0) : (b2 + (c0 - 256));
    unsigned short os[8];
#pragma unroll
    for (int j = 0; j < 8; j++) {
        acc[j] = fmaf(si, bf2f(U.u[j]), acc[j]) + bp[j];
        os[j] = f2bf(acc[j]);
    }
    int4 ov;
    ov.x = (int)(((unsigned)os[1] << 16) | os[0]);
    ov.y = (int)(((unsigned)os[3] << 16) | os[2]);
    ov.z = (int)(((unsigned)os[5] << 16) | os[4]);
    ov.w = (int)(((unsigned)os[7] << 16) | os[6]);
    *(int4*)(&hagg[(size_t)n * 512 + c0]) = ov;
}

// ---------------- BN stats over bf16 [N][512] (LDS-reduced, 128 atomics/addr) ----------
__global__ __launch_bounds__(256) void bn_stats2(const unsigned short* __restrict__ h,
                                                 float* __restrict__ stats) {
    __shared__ float sh[4][1024];
    int t = threadIdx.x;
    int wv = t >> 6, l = t & 63;
    int c0 = l * 8;
    float s[8] = {}, q[8] = {};
    for (int n = blockIdx.x * 4 + wv; n < N_NODES; n += STAT_BLOCKS * 4) {
        union { int4 v; unsigned short u[8]; } U;
        U.v = *(const int4*)(&h[(size_t)n * 512 + c0]);
#pragma unroll
        for (int j = 0; j < 8; j++) {
            float x = bf2f(U.u[j]);
            s[j] += x;
            q[j] = fmaf(x, x, q[j]);
        }
    }
#pragma unroll
    for (int j = 0; j < 8; j++) {
        sh[wv][c0 + j] = s[j];
        sh[wv][512 + c0 + j] = q[j];
    }
    __syncthreads();
    for (int i = t; i < 1024; i += 256) {
        float a = sh[0][i] + sh[1][i] + sh[2][i] + sh[3][i];
        atomicAdd(&stats[i], a);
    }
}

// stats -> per-channel affine AB; also re-zeros stats for the next layer
__global__ __launch_bounds__(256) void bn_ab(const float* __restrict__ stats,
                                             const float* __restrict__ g,
                                             const float* __restrict__ be,
                                             float* __restrict__ AB,
                                             float* __restrict__ stats_mut) {
    int t = threadIdx.x;
#pragma unroll
    for (int h = 0; h < 2; h++) {
        int c = t + h * 256;
        float m = stats[c] * (1.0f / N_NODES);
        float var = stats[512 + c] * (1.0f / N_NODES) - m * m;
        float sc = g[c & 255] * rsqrtf(var + BN_EPS);
        AB[c] = sc;
        AB[512 + c] = be[c & 255] - m * sc;
        stats_mut[c] = 0.0f;
        stats_mut[512 + c] = 0.0f;
    }
}

// y = relu(x*A + B), bf16 in/out, 512-wide
__global__ __launch_bounds__(256) void bn_apply(const unsigned short* __restrict__ h,
                                                const float* __restrict__ AB,
                                                unsigned short* __restrict__ outp) {
    int i8 = blockIdx.x * blockDim.x + threadIdx.x;
    if (i8 >= N_NODES * 512 / 8) return;
    int c8 = (i8 & 63) * 8;
    union { int4 v; unsigned short u[8]; } U;
    U.v = *(const int4*)(&h[(size_t)i8 * 8]);
    unsigned short os[8];
#pragma unroll
    for (int j = 0; j < 8; j++) {
        int c = c8 + j;
        float y = fmaf(bf2f(U.u[j]), AB[c], AB[512 + c]);
        os[j] = f2bf(fmaxf(y, 0.0f));
    }
    int4 ov;
    ov.x = (int)(((unsigned)os[1] << 16) | os[0]);
    ov.y = (int)(((unsigned)os[3] << 16) | os[2]);
    ov.z = (int)(((unsigned)os[5] << 16) | os[4]);
    ov.w = (int)(((unsigned)os[7] << 16) | os[6]);
    *(int4*)(&outp[(size_t)i8 * 8]) = ov;
}

// final: hc = relu(bn(h1)) + relu(bn(h2)), bf16 out 256-wide
__global__ __launch_bounds__(256) void bn_apply_final(const unsigned short* __restrict__ h,
                                                      const float* __restrict__ AB,
                                                      unsigned short* __restrict__ hc) {
    int i8 = blockIdx.x * blockDim.x + threadIdx.x;
    if (i8 >= N_NODES * 256 / 8) return;
    int n = i8 >> 5;
    int c8 = (i8 & 31) * 8;
    union { int4 v; unsigned short u[8]; } U1, U2;
    U1.v = *(const int4*)(&h[(size_t)n * 512 + c8]);
    U2.v = *(const int4*)(&h[(size_t)n * 512 + 256 + c8]);
    unsigned short os[8];
#pragma unroll
    for (int j = 0; j < 8; j++) {
        int c = c8 + j;
        float y1 = fmaxf(fmaf(bf2f(U1.u[j]), AB[c], AB[512 + c]), 0.0f);
        int c2 = c + 256;
        float y2 = fmaxf(fmaf(bf2f(U2.u[j]), AB[c2], AB[512 + c2]), 0.0f);
        os[j] = f2bf(y1 + y2);
    }
    int4 ov;
    ov.x = (int)(((unsigned)os[1] << 16) | os[0]);
    ov.y = (int)(((unsigned)os[3] << 16) | os[2]);
    ov.z = (int)(((unsigned)os[5] << 16) | os[4]);
    ov.w = (int)(((unsigned)os[7] << 16) | os[6]);
    *(int4*)(&hc[(size_t)i8 * 8]) = ov;
}

// ---------------- launch ----------------
extern "C" void kernel_launch(void* const* d_in, const int* in_sizes, int n_in,
                              void* d_out, int out_size, void* d_ws, size_t ws_size,
                              hipStream_t stream) {
    const float* x   = (const float*)d_in[0];
    const int*   ei  = (const int*)d_in[1];
    const float* ea  = (const float*)d_in[2];
    const float* W11 = (const float*)d_in[3];
    const float* b11 = (const float*)d_in[4];
    const float* W12 = (const float*)d_in[5];
    const float* b12 = (const float*)d_in[6];
    const float* W13 = (const float*)d_in[7];
    const float* b13 = (const float*)d_in[8];
    const float* W21 = (const float*)d_in[9];
    const float* b21 = (const float*)d_in[10];
    const float* W22 = (const float*)d_in[11];
    const float* b22 = (const float*)d_in[12];
    const float* W23 = (const float*)d_in[13];
    const float* b23 = (const float*)d_in[14];
    const float* g1  = (const float*)d_in[15];
    const float* be1 = (const float*)d_in[16];
    const float* g2  = (const float*)d_in[17];
    const float* be2 = (const float*)d_in[18];
    const float* g3  = (const float*)d_in[19];
    const float* be3 = (const float*)d_in[20];
    const float* Wc1 = (const float*)d_in[21];
    const float* bc1 = (const float*)d_in[22];
    const float* Wc2 = (const float*)d_in[23];
    const float* bc2 = (const float*)d_in[24];
    const float* Wc3 = (const float*)d_in[25];
    const float* bc3 = (const float*)d_in[26];
    const float* Wc4 = (const float*)d_in[27];
    const float* bc4 = (const float*)d_in[28];
    const float* Wc5 = (const float*)d_in[29];
    const float* bc5 = (const float*)d_in[30];

    const int* src = ei;
    const int* dst = ei + N_EDGES;
    float* out = (float*)d_out;

    // ---- workspace carve ----
    char* w = (char*)d_ws;
    auto alloc = [&](size_t bytes) {
        char* p = w;
        w += (bytes + 255) & ~(size_t)255;
        return p;
    };
    float* isd     = (float*)alloc(N_NODES * 4);
    int2*  pk      = (int2*)alloc((size_t)N_EDGES * 8);
    int*   edstA   = (int*)alloc((size_t)N_EDGES * 4);
    int*   eorigA  = (int*)alloc((size_t)N_EDGES * 4);
    int*   counts  = (int*)alloc((N_NODES + 4) * 4);
    int*   offsets = (int*)alloc((N_NODES + 4) * 4);
    int*   bsum    = (int*)alloc(256 * 4);
    int*   boff    = (int*)alloc(256 * 4);
    float* stats   = (float*)alloc(1024 * 4);
    float* AB      = (float*)alloc(1024 * 4);
    unsigned short* W11t = (unsigned short*)alloc(256 * 128 * 2);
    unsigned short* W21t = (unsigned short*)alloc(256 * 128 * 2);
    unsigned short* W12t = (unsigned short*)alloc(256 * 256 * 2);
    unsigned short* W22t = (unsigned short*)alloc(256 * 256 * 2);
    unsigned short* W13t = (unsigned short*)alloc(256 * 256 * 2);
    unsigned short* W23t = (unsigned short*)alloc(256 * 256 * 2);
    unsigned short* WPQt = (unsigned short*)alloc(512 * 256 * 2);
    unsigned short* Wc2t = (unsigned short*)alloc(256 * 256 * 2);
    unsigned short* Wc3t = (unsigned short*)alloc(128 * 256 * 2);
    unsigned short* Wc4t = (unsigned short*)alloc(64 * 128 * 2);
    unsigned short* xb   = (unsigned short*)alloc((size_t)N_NODES * 128 * 2);
    unsigned short* hb   = (unsigned short*)alloc((size_t)N_NODES * 512 * 2);
    unsigned short* hwb  = (unsigned short*)alloc((size_t)N_NODES * 512 * 2);
    unsigned short* hagg = (unsigned short*)alloc((size_t)N_NODES * 512 * 2);
    unsigned short* hc   = (unsigned short*)alloc((size_t)N_NODES * 256 * 2);
    (void)ws_size;

    // ---- CSR build ----
    zero_i32<<<(N_NODES + 256) / 256, 256, 0, stream>>>(counts, N_NODES + 1);
    count_deg<<<(N_EDGES + 255) / 256, 256, 0, stream>>>(dst, counts);
    isd_kernel<<<(N_NODES + 255) / 256, 256, 0, stream>>>(counts, isd);
    scan_reduce<<<NB_SCAN, 256, 0, stream>>>(counts, bsum);
    scan_tops<<<1, 256, 0, stream>>>(bsum, boff, NB_SCAN, offsets + N_NODES);
    scan_final<<<NB_SCAN, 256, 0, stream>>>(counts, boff, offsets);
    zero_i32<<<(N_NODES + 255) / 256, 256, 0, stream>>>(counts, N_NODES);
    fill_csr<<<(N_EDGES + 255) / 256, 256, 0, stream>>>(src, dst, isd, offsets, counts,
                                                        pk, edstA, eorigA);

    // ---- preconvert (x -> bf16; all 11 weight transposes in ONE dispatch) ----
    conv_f32_bf16<<<(N_NODES * 128 / 4 + 255) / 256, 256, 0, stream>>>(x, xb,
                                                                        N_NODES * 128 / 4);
    WPack wp;
    wp.src[0] = W11; wp.dst[0] = W11t;
    wp.src[1] = W21; wp.dst[1] = W21t;
    wp.src[2] = W12; wp.dst[2] = W12t;
    wp.src[3] = W22; wp.dst[3] = W22t;
    wp.src[4] = W13; wp.dst[4] = W13t;
    wp.src[5] = W23; wp.dst[5] = W23t;
    wp.src[6] = Wc1; wp.dst[6] = WPQt;
    wp.src[7] = Wc1 + 256 * 256; wp.dst[7] = WPQt + 256 * 256;
    wp.src[8] = Wc2; wp.dst[8] = Wc2t;
    wp.src[9] = Wc3; wp.dst[9] = Wc3t;
    wp.src[10] = Wc4; wp.dst[10] = Wc4t;
    prep_weights<<<dim3(256, 11), 256, 0, stream>>>(wp);

    // stats zero (post-poison init; bn_ab re-zeros between layers)
    zero_f32<<<4, 256, 0, stream>>>(stats, 1024);

    // ---- 3 GCN layers (dual-branch GEMM in one dispatch) ----
    const unsigned short* Wat[3] = {W11t, W12t, W13t};
    const unsigned short* Wbt[3] = {W21t, W22t, W23t};
    const float* ba[3] = {b11, b12, b13};
    const float* bb[3] = {b21, b22, b23};
    const float* gs[3] = {g1, g2, g3};
    const float* bes[3] = {be1, be2, be3};

    int gx_n = (N_NODES + 127) / 128;  // 391
    for (int l = 0; l < 3; l++) {
        if (l == 0) {
            gemm_mfma<128, 1, 0, 0, 1><<<dim3(gx_n, 4), 256, 0, stream>>>(
                xb, 128, Wat[0], nullptr, hwb, 512, N_NODES, 128, xb, Wbt[0]);
        } else {
            gemm_mfma<128, 1, 0, 0, 1><<<dim3(gx_n, 4), 256, 0, stream>>>(
                hb, 512, Wat[l], nullptr, hwb, 512, N_NODES, 256, hb + 256, Wbt[l]);
        }
        aggregate2<<<N_NODES / 4, 256, 0, stream>>>(hwb, isd, offsets, pk,
                                                    ba[l], bb[l], hagg);
        bn_stats2<<<STAT_BLOCKS, 256, 0, stream>>>(hagg, stats);
        bn_ab<<<1, 256, 0, stream>>>(stats, gs[l], bes[l], AB, stats);
        if (l < 2) {
            bn_apply<<<(N_NODES * 512 / 8 + 255) / 256, 256, 0, stream>>>(hagg, AB, hb);
        } else {
            bn_apply_final<<<(N_NODES * 256 / 8 + 255) / 256, 256, 0, stream>>>(hagg, AB, hc);
        }
    }

    // ---- PQ = hc @ [Wc1_P | Wc1_Q] -> hwb [N][512] bf16 ----
    gemm_mfma<128, 1, 0, 0, 0><<<dim3(gx_n, 4), 256, 0, stream>>>(hc, 256, WPQt, nullptr,
                                                                  hwb, 512, N_NODES, 256,
                                                                  nullptr, nullptr);

    // ---- fused edge MLP: one dispatch, all 400K edges ----
    edge_mlp_fused<<<N_EDGES / EPB, 512, 0, stream>>>(
        hwb, pk, edstA, eorigA, ea, Wc1 + 512 * 256, bc1,
        Wc2t, bc2, Wc3t, bc3, Wc4t, bc4, Wc5, bc5, out);
}

// Round 11
// 730.926 us; speedup vs baseline: 40.0951x; 1.0186x over previous
//
#include <hip/hip_runtime.h>

#define N_NODES 50000
#define N_EDGES 400000
#define EPB     128          // edges per block in fused edge MLP
#define NB_SCAN 196
#define BN_EPS  1e-5f
#define STAT_BLOCKS 128

typedef __attribute__((ext_vector_type(8))) short s16x8;
typedef __attribute__((ext_vector_type(4))) float f32x4;

__device__ __forceinline__ unsigned short f2bf(float x) {
    unsigned u = __float_as_uint(x);
    return (unsigned short)((u + 0x7fffu + ((u >> 16) & 1u)) >> 16);
}
__device__ __forceinline__ float bf2f(unsigned short b) {
    return __uint_as_float(((unsigned)b) << 16);
}

// direct global->LDS 16B load (linear LDS dest = wave base + lane*16)
__device__ __forceinline__ void gload_lds16(const void* g, void* lds) {
    auto gp = reinterpret_cast<const __attribute__((address_space(1))) unsigned int*>(
        reinterpret_cast<uintptr_t>(g));
    auto lp = reinterpret_cast<__attribute__((address_space(3))) unsigned int*>(
        reinterpret_cast<uintptr_t>(lds));
    __builtin_amdgcn_global_load_lds(gp, lp, 16, 0, 0);
}

// ---------------- utility ----------------
__global__ void zero_i32(int* p, int n) {
    int i = blockIdx.x * blockDim.x + threadIdx.x;
    if (i < n) p[i] = 0;
}
__global__ void zero_f32(float* p, int n) {
    int i = blockIdx.x * blockDim.x + threadIdx.x;
    if (i < n) p[i] = 0.0f;
}
__global__ void count_deg(const int* __restrict__ dst, int* __restrict__ counts) {
    int e = blockIdx.x * blockDim.x + threadIdx.x;
    if (e < N_EDGES) atomicAdd(&counts[dst[e]], 1);
}
__global__ void isd_kernel(const int* __restrict__ counts, float* __restrict__ isd) {
    int i = blockIdx.x * blockDim.x + threadIdx.x;
    if (i < N_NODES) isd[i] = rsqrtf(1.0f + (float)counts[i]);
}

// ---------------- 3-phase scan ----------------
__global__ __launch_bounds__(256) void scan_reduce(const int* __restrict__ counts,
                                                   int* __restrict__ bsum) {
    __shared__ int sh[256];
    int t = threadIdx.x, b = blockIdx.x;
    int i = b * 256 + t;
    sh[t] = (i < N_NODES) ? counts[i] : 0;
    __syncthreads();
    for (int o = 128; o > 0; o >>= 1) {
        if (t < o) sh[t] += sh[t + o];
        __syncthreads();
    }
    if (t == 0) bsum[b] = sh[0];
}
__global__ __launch_bounds__(256) void scan_tops(const int* __restrict__ bsum,
                                                 int* __restrict__ boff, int nb,
                                                 int* __restrict__ total_out) {
    __shared__ int sh[256];
    int t = threadIdx.x;
    int v = (t < nb) ? bsum[t] : 0;
    sh[t] = v;
    __syncthreads();
    for (int o = 1; o < 256; o <<= 1) {
        int a = (t >= o) ? sh[t - o] : 0;
        __syncthreads();
        sh[t] += a;
        __syncthreads();
    }
    if (t < nb) boff[t] = sh[t] - v;
    if (t == 255) *total_out = sh[255];
}
__global__ __launch_bounds__(256) void scan_final(const int* __restrict__ counts,
                                                  const int* __restrict__ boff,
                                                  int* __restrict__ offsets) {
    __shared__ int sh[256];
    int t = threadIdx.x, b = blockIdx.x;
    int i = b * 256 + t;
    int v = (i < N_NODES) ? counts[i] : 0;
    sh[t] = v;
    __syncthreads();
    for (int o = 1; o < 256; o <<= 1) {
        int a = (t >= o) ? sh[t - o] : 0;
        __syncthreads();
        sh[t] += a;
        __syncthreads();
    }
    if (i < N_NODES) offsets[i] = boff[b] + sh[t] - v;
}

// packed CSR entry: (src, norm) as int2; also dst and orig-edge-id per CSR slot
__global__ void fill_csr(const int* __restrict__ src, const int* __restrict__ dst,
                         const float* __restrict__ isd, const int* __restrict__ offsets,
                         int* __restrict__ cursor, int2* __restrict__ pk,
                         int* __restrict__ edstA, int* __restrict__ eorigA) {
    int e = blockIdx.x * blockDim.x + threadIdx.x;
    if (e >= N_EDGES) return;
    int s = src[e], d = dst[e];
    int pos = offsets[d] + atomicAdd(&cursor[d], 1);
    pk[pos] = make_int2(s, __float_as_int(isd[s] * isd[d]));
    edstA[pos] = d;
    eorigA[pos] = e;
}

// ---------------- conversions ----------------
__global__ void conv_f32_bf16(const float* __restrict__ in, unsigned short* __restrict__ out,
                              int n4) {
    int i = blockIdx.x * blockDim.x + threadIdx.x;
    if (i >= n4) return;
    float4 v = ((const float4*)in)[i];
    unsigned short o0 = f2bf(v.x), o1 = f2bf(v.y), o2 = f2bf(v.z), o3 = f2bf(v.w);
    ((uint2*)out)[i] = make_uint2(((unsigned)o1 << 16) | o0, ((unsigned)o3 << 16) | o2);
}

// all 11 weight transposes (fp32 [K][N] -> bf16 [N][K]) in one dispatch
struct WPack {
    const float* src[11];
    unsigned short* dst[11];
};
__global__ __launch_bounds__(256) void prep_weights(WPack p) {
    const int Ks[11] = {128, 128, 256, 256, 256, 256, 256, 256, 256, 256, 128};
    const int Ns[11] = {256, 256, 256, 256, 256, 256, 256, 256, 256, 128, 64};
    int seg = blockIdx.y;
    int K = Ks[seg], N = Ns[seg];
    int idx = blockIdx.x * 256 + threadIdx.x;
    if (idx >= K * N) return;
    int k = idx / N, n = idx % N;
    p.dst[seg][(size_t)n * K + k] = f2bf(p.src[seg][idx]);
}

// ---------------- bf16 MFMA GEMM (global_load_lds staging) ----------------
// C[M][Nout] = A[M][K] @ Wt[Nout][K]^T. OUT_MODE: 0=f32, 1=bf16.
// DUAL: grid.y=4, half=(y>>1) selects {A,Wt,bias} vs {A2,Wt2,bias2}, col offset half*256.
template <int BN_T, int OUT_MODE, int RELU, int BIAS, int DUAL>
__global__ __launch_bounds__(256) void gemm_mfma(const unsigned short* __restrict__ A, int lda,
                                                 const unsigned short* __restrict__ Wt,
                                                 const float* __restrict__ bias,
                                                 void* __restrict__ Cout, int ldc,
                                                 int M, int K,
                                                 const unsigned short* __restrict__ A2,
                                                 const unsigned short* __restrict__ Wt2,
                                                 const float* __restrict__ bias2) {
    constexpr int MI = (BN_T == 128) ? 4 : 2;
    constexpr int NI = 4;
    __shared__ __align__(16) short As[128 * 32];
    __shared__ __align__(16) short Bs[BN_T * 32];

    const int tid = threadIdx.x;
    const int l = tid & 63;
    const int wv = tid >> 6;
    const int wrow = (BN_T == 128) ? (wv >> 1) * 64 : wv * 32;
    const int wcol = (BN_T == 128) ? (wv & 1) * 64 : 0;
    const int bm = blockIdx.x * 128;
    int bn, coloff;
    int half_ = 0;
    const unsigned short* Ause;
    const unsigned short* Wuse;
    if (DUAL) {
        half_ = blockIdx.y >> 1;
        bn = (blockIdx.y & 1) * BN_T;
        coloff = half_ * 256;
        Ause = half_ ? A2 : A;
        Wuse = half_ ? Wt2 : Wt;
    } else {
        bn = blockIdx.y * BN_T;
        coloff = 0;
        Ause = A;
        Wuse = Wt;
    }
    const int rsub = l >> 2;
    const int gl = l & 3;

    f32x4 acc[MI][NI] = {};

    for (int k0 = 0; k0 < K; k0 += 32) {
#pragma unroll
        for (int i = 0; i < 2; i++) {
            int lr = wv * 32 + i * 16 + rsub;
            int gr = bm + lr;
            if (gr >= M) gr = M - 1;
            int gsrc = gl ^ ((lr >> 1) & 3);
            gload_lds16(&Ause[(size_t)gr * lda + k0 + gsrc * 8],
                        &As[(wv * 32 + i * 16) * 32]);
        }
#pragma unroll
        for (int i = 0; i < BN_T / 64; i++) {
            int base = (BN_T == 128) ? (wv * 32 + i * 16) : (wv * 16);
            int lr = base + rsub;
            int gsrc = gl ^ ((lr >> 1) & 3);
            gload_lds16(&Wuse[(size_t)(bn + lr) * K + k0 + gsrc * 8],
                        &Bs[base * 32]);
        }
        __syncthreads();

        s16x8 af[MI], bfr[NI];
        const int q = l >> 4;
#pragma unroll
        for (int mi = 0; mi < MI; mi++) {
            int r = wrow + mi * 16 + (l & 15);
            af[mi] = *(const s16x8*)(&As[r * 32 + ((q ^ ((r >> 1) & 3)) << 3)]);
        }
#pragma unroll
        for (int ni = 0; ni < NI; ni++) {
            int r = wcol + ni * 16 + (l & 15);
            bfr[ni] = *(const s16x8*)(&Bs[r * 32 + ((q ^ ((r >> 1) & 3)) << 3)]);
        }
#pragma unroll
        for (int mi = 0; mi < MI; mi++)
#pragma unroll
            for (int ni = 0; ni < NI; ni++)
                acc[mi][ni] = __builtin_amdgcn_mfma_f32_16x16x32_bf16(af[mi], bfr[ni],
                                                                      acc[mi][ni], 0, 0, 0);
        __syncthreads();
    }

#pragma unroll
    for (int mi = 0; mi < MI; mi++) {
#pragma unroll
        for (int ni = 0; ni < NI; ni++) {
            int colL = bn + wcol + ni * 16 + (l & 15);
            int colB = coloff + colL;
            float bv = 0.0f;
            if (BIAS) {
                if (DUAL) {
                    const float* bp = half_ ? bias2 : bias;
                    bv = bp[colL];
                } else {
                    bv = bias[colB];
                }
            }
#pragma unroll
            for (int r = 0; r < 4; r++) {
                int row = bm + wrow + mi * 16 + (l >> 4) * 4 + r;
                if (row < M) {
                    float v = acc[mi][ni][r] + bv;
                    if (RELU) v = fmaxf(v, 0.0f);
                    if (OUT_MODE == 1)
                        ((unsigned short*)Cout)[(size_t)row * ldc + colB] = f2bf(v);
                    else
                        ((float*)Cout)[(size_t)row * ldc + colB] = v;
                }
            }
        }
    }
}

// ---------------- fused edge MLP megakernel (128 edges, 512 threads) ----------------
__global__ __launch_bounds__(512, 4) void edge_mlp_fused(
    const unsigned short* __restrict__ PQ, const int2* __restrict__ pk,
    const int* __restrict__ edstA, const int* __restrict__ eorigA,
    const float* __restrict__ ea, const float* __restrict__ Wc1e,
    const float* __restrict__ bc1,
    const unsigned short* __restrict__ Wc2t, const float* __restrict__ bc2,
    const unsigned short* __restrict__ Wc3t, const float* __restrict__ bc3,
    const unsigned short* __restrict__ Wc4t, const float* __restrict__ bc4,
    const float* __restrict__ Wc5, const float* __restrict__ bc5,
    float* __restrict__ out) {
    __shared__ __align__(16) short At[EPB * 256];  // 64KB, swizzled [row][ch]
    __shared__ __align__(16) short Bs[256 * 32];   // 16KB weight staging

    const int tid = threadIdx.x;
    const int l = tid & 63;
    const int wv = tid >> 6;           // 0..7
    const int p0 = blockIdx.x * EPB;
    const int lm = l & 15;
    const int q = l >> 4;
    const int rsub = l >> 2;
    const int gl = l & 3;

    // ---- phase 0: gather + edge layer 1 -> At (row=edge, ch=0..255) ----
    {
        const int c0 = l * 4;
        float bi0 = bc1[c0], bi1 = bc1[c0 + 1], bi2 = bc1[c0 + 2], bi3 = bc1[c0 + 3];
        float4 w8[8];
#pragma unroll
        for (int jj = 0; jj < 8; jj++) w8[jj] = *(const float4*)(&Wc1e[jj * 256 + c0]);
        const int g = l >> 1;
        const int sub = (l & 1) * 4;
#pragma unroll 4
        for (int i = 0; i < 16; i++) {
            int row = wv * 16 + i;
            int p = p0 + row;
            int s = pk[p].x;
            int d = edstA[p];
            int eo = eorigA[p];
            union { int2 v; unsigned short u[4]; } Pu, Qu;
            Pu.v = *(const int2*)(&PQ[(size_t)s * 512 + c0]);
            Qu.v = *(const int2*)(&PQ[(size_t)d * 512 + 256 + c0]);
            float v0 = bf2f(Pu.u[0]) + bf2f(Qu.u[0]) + bi0;
            float v1 = bf2f(Pu.u[1]) + bf2f(Qu.u[1]) + bi1;
            float v2 = bf2f(Pu.u[2]) + bf2f(Qu.u[2]) + bi2;
            float v3 = bf2f(Pu.u[3]) + bf2f(Qu.u[3]) + bi3;
#pragma unroll
            for (int jj = 0; jj < 8; jj++) {
                float av = ea[(size_t)eo * 8 + jj];
                v0 = fmaf(av, w8[jj].x, v0);
                v1 = fmaf(av, w8[jj].y, v1);
                v2 = fmaf(av, w8[jj].z, v2);
                v3 = fmaf(av, w8[jj].w, v3);
            }
            unsigned short o0 = f2bf(fmaxf(v0, 0.0f)), o1 = f2bf(fmaxf(v1, 0.0f));
            unsigned short o2 = f2bf(fmaxf(v2, 0.0f)), o3 = f2bf(fmaxf(v3, 0.0f));
            int off = row * 256 + ((g ^ (row & 7)) << 3) + sub;
            *(uint2*)(&At[off]) =
                make_uint2(((unsigned)o1 << 16) | o0, ((unsigned)o3 << 16) | o2);
        }
    }
    __syncthreads();

    // ---- GEMM1: [128x256] = relu(At @ Wc2t^T + bc2) -> At ----
    {
        const int wrow = (wv >> 2) * 64;   // 0,64
        const int wcol = (wv & 3) * 64;    // 0,64,128,192
        f32x4 acc[4][4] = {};
        for (int k0 = 0; k0 < 256; k0 += 32) {
#pragma unroll
            for (int i = 0; i < 2; i++) {
                int lr = wv * 32 + i * 16 + rsub;
                int gsrc = gl ^ ((lr >> 1) & 3);
                gload_lds16(&Wc2t[(size_t)lr * 256 + k0 + gsrc * 8],
                            &Bs[(wv * 32 + i * 16) * 32]);
            }
            __syncthreads();
            s16x8 af[4], bfr[4];
#pragma unroll
            for (int mi = 0; mi < 4; mi++) {
                int r = wrow + mi * 16 + lm;
                int G = (k0 >> 3) + q;
                af[mi] = *(const s16x8*)(&At[r * 256 + ((G ^ (r & 7)) << 3)]);
            }
#pragma unroll
            for (int ni = 0; ni < 4; ni++) {
                int rb = wcol + ni * 16 + lm;
                bfr[ni] = *(const s16x8*)(&Bs[rb * 32 + ((q ^ ((rb >> 1) & 3)) << 3)]);
            }
#pragma unroll
            for (int mi = 0; mi < 4; mi++)
#pragma unroll
                for (int ni = 0; ni < 4; ni++)
                    acc[mi][ni] = __builtin_amdgcn_mfma_f32_16x16x32_bf16(
                        af[mi], bfr[ni], acc[mi][ni], 0, 0, 0);
            __syncthreads();
        }
        // epilogue back into At (all reads complete after final barrier)
#pragma unroll
        for (int mi = 0; mi < 4; mi++) {
#pragma unroll
            for (int ni = 0; ni < 4; ni++) {
                int col = wcol + ni * 16 + lm;
                float bv = bc2[col];
#pragma unroll
                for (int r = 0; r < 4; r++) {
                    int row = wrow + mi * 16 + q * 4 + r;
                    At[row * 256 + (((col >> 3) ^ (row & 7)) << 3) + (col & 7)] =
                        (short)f2bf(fmaxf(acc[mi][ni][r] + bv, 0.0f));
                }
            }
        }
    }
    __syncthreads();

    // ---- GEMM2: [128x128] = relu(A2 @ Wc3t^T + bc3) -> At (stride 128) ----
    {
        const int wrow = (wv >> 1) * 32;   // 0,32,64,96
        const int wcol = (wv & 1) * 64;    // 0,64
        f32x4 acc[2][4] = {};
        for (int k0 = 0; k0 < 256; k0 += 32) {
            {
                int lr = wv * 16 + rsub;
                int gsrc = gl ^ ((lr >> 1) & 3);
                gload_lds16(&Wc3t[(size_t)lr * 256 + k0 + gsrc * 8],
                            &Bs[(wv * 16) * 32]);
            }
            __syncthreads();
            s16x8 af[2], bfr[4];
#pragma unroll
            for (int mi = 0; mi < 2; mi++) {
                int r = wrow + mi * 16 + lm;
                int G = (k0 >> 3) + q;
                af[mi] = *(const s16x8*)(&At[r * 256 + ((G ^ (r & 7)) << 3)]);
            }
#pragma unroll
            for (int ni = 0; ni < 4; ni++) {
                int rb = wcol + ni * 16 + lm;
                bfr[ni] = *(const s16x8*)(&Bs[rb * 32 + ((q ^ ((rb >> 1) & 3)) << 3)]);
            }
#pragma unroll
            for (int mi = 0; mi < 2; mi++)
#pragma unroll
                for (int ni = 0; ni < 4; ni++)
                    acc[mi][ni] = __builtin_amdgcn_mfma_f32_16x16x32_bf16(
                        af[mi], bfr[ni], acc[mi][ni], 0, 0, 0);
            __syncthreads();
        }
#pragma unroll
        for (int mi = 0; mi < 2; mi++) {
#pragma unroll
            for (int ni = 0; ni < 4; ni++) {
                int col = wcol + ni * 16 + lm;
                float bv = bc3[col];
#pragma unroll
                for (int r = 0; r < 4; r++) {
                    int row = wrow + mi * 16 + q * 4 + r;
                    At[row * 128 + (((col >> 3) ^ (row & 7)) << 3) + (col & 7)] =
                        (short)f2bf(fmaxf(acc[mi][ni][r] + bv, 0.0f));
                }
            }
        }
    }
    __syncthreads();

    // ---- GEMM3: [128x64] = A3 @ Wc4t^T, fused relu+bc4 then @Wc5 + bc5, scatter ----
    {
        const int wrow = wv * 16;
        f32x4 acc[4] = {};
        for (int k0 = 0; k0 < 128; k0 += 32) {
            if (wv < 4) {
                int lr = wv * 16 + rsub;
                int gsrc = gl ^ ((lr >> 1) & 3);
                gload_lds16(&Wc4t[(size_t)lr * 128 + k0 + gsrc * 8],
                            &Bs[(wv * 16) * 32]);
            }
            __syncthreads();
            s16x8 af, bfr[4];
            {
                int r = wrow + lm;
                int G = (k0 >> 3) + q;
                af = *(const s16x8*)(&At[r * 128 + ((G ^ (r & 7)) << 3)]);
            }
#pragma unroll
            for (int ni = 0; ni < 4; ni++) {
                int rb = ni * 16 + lm;
                bfr[ni] = *(const s16x8*)(&Bs[rb * 32 + ((q ^ ((rb >> 1) & 3)) << 3)]);
            }
#pragma unroll
            for (int ni = 0; ni < 4; ni++)
                acc[ni] = __builtin_amdgcn_mfma_f32_16x16x32_bf16(af, bfr[ni],
                                                                  acc[ni], 0, 0, 0);
            __syncthreads();
        }
#pragma unroll
        for (int r = 0; r < 4; r++) {
            float pa = 0.f, pb = 0.f;
#pragma unroll
            for (int ni = 0; ni < 4; ni++) {
                int col = ni * 16 + lm;
                float v = fmaxf(acc[ni][r] + bc4[col], 0.0f);
                pa = fmaf(v, Wc5[col * 2 + 0], pa);
                pb = fmaf(v, Wc5[col * 2 + 1], pb);
            }
#pragma unroll
            for (int o = 1; o < 16; o <<= 1) {
                pa += __shfl_xor(pa, o, 64);
                pb += __shfl_xor(pb, o, 64);
            }
            if (lm == 0) {
                int row = wrow + q * 4 + r;
                int eo = eorigA[p0 + row];
                out[(size_t)eo * 2 + 0] = pa + bc5[0];
                out[(size_t)eo * 2 + 1] = pb + bc5[1];
            }
        }
    }
}

// ---------------- GCN aggregation: 1 node/wave, packed pairs, bf16 out ----------------
__global__ __launch_bounds__(256) void aggregate2(const unsigned short* __restrict__ hwb,
                                                  const float* __restrict__ isd,
                                                  const int* __restrict__ offsets,
                                                  const int2* __restrict__ pk,
                                                  const float* __restrict__ b1,
                                                  const float* __restrict__ b2,
                                                  unsigned short* __restrict__ hagg) {
    int wv = threadIdx.x >> 6, l = threadIdx.x & 63;
    int n = blockIdx.x * 4 + wv;
    int c0 = l * 8;
    float acc[8] = {};
    int e0 = offsets[n], e1 = offsets[n + 1];
    int k = e0;
    for (; k + 2 <= e1; k += 2) {
        int2 p0 = pk[k], p1 = pk[k + 1];
        union { int4 v; unsigned short u[8]; } U0, U1;
        U0.v = *(const int4*)(&hwb[(size_t)p0.x * 512 + c0]);
        U1.v = *(const int4*)(&hwb[(size_t)p1.x * 512 + c0]);
        float w0 = __int_as_float(p0.y), w1 = __int_as_float(p1.y);
#pragma unroll
        for (int j = 0; j < 8; j++)
            acc[j] = fmaf(w0, bf2f(U0.u[j]), fmaf(w1, bf2f(U1.u[j]), acc[j]));
    }
    if (k < e1) {
        int2 p0 = pk[k];
        union { int4 v; unsigned short u[8]; } U0;
        U0.v = *(const int4*)(&hwb[(size_t)p0.x * 512 + c0]);
        float w0 = __int_as_float(p0.y);
#pragma unroll
        for (int j = 0; j < 8; j++) acc[j] = fmaf(w0, bf2f(U0.u[j]), acc[j]);
    }
    float si = isd[n]; si *= si;
    union { int4 v; unsigned short u[8]; } U;
    U.v = *(const int4*)(&hwb[(size_t)n * 512 + c0]);
    const float* bp = (c0 < 256) ? (b1 + c0) : (b2 + (c0 - 256));
    unsigned short os[8];
#pragma unroll
    for (int j = 0; j < 8; j++) {
        acc[j] = fmaf(si, bf2f(U.u[j]), acc[j]) + bp[j];
        os[j] = f2bf(acc[j]);
    }
    int4 ov;
    ov.x = (int)(((unsigned)os[1] << 16) | os[0]);
    ov.y = (int)(((unsigned)os[3] << 16) | os[2]);
    ov.z = (int)(((unsigned)os[5] << 16) | os[4]);
    ov.w = (int)(((unsigned)os[7] << 16) | os[6]);
    *(int4*)(&hagg[(size_t)n * 512 + c0]) = ov;
}

// ---------------- layer-0 aggregation on x (128 ch, bf16), no bias ----------------
__global__ __launch_bounds__(256) void aggregate128(const unsigned short* __restrict__ xb,
                                                    const float* __restrict__ isd,
                                                    const int* __restrict__ offsets,
                                                    const int2* __restrict__ pk,
                                                    unsigned short* __restrict__ hagg0) {
    int wv = threadIdx.x >> 6, l = threadIdx.x & 63;
    int n = blockIdx.x * 4 + wv;
    int c0 = l * 2;
    float a0 = 0.f, a1 = 0.f;
    int e0 = offsets[n], e1 = offsets[n + 1];
    int k = e0;
    for (; k + 2 <= e1; k += 2) {
        int2 p0 = pk[k], p1 = pk[k + 1];
        unsigned u0 = *(const unsigned*)(&xb[(size_t)p0.x * 128 + c0]);
        unsigned u1 = *(const unsigned*)(&xb[(size_t)p1.x * 128 + c0]);
        float w0 = __int_as_float(p0.y), w1 = __int_as_float(p1.y);
        a0 = fmaf(w0, bf2f((unsigned short)u0), fmaf(w1, bf2f((unsigned short)u1), a0));
        a1 = fmaf(w0, bf2f((unsigned short)(u0 >> 16)),
                  fmaf(w1, bf2f((unsigned short)(u1 >> 16)), a1));
    }
    if (k < e1) {
        int2 p0 = pk[k];
        unsigned u0 = *(const unsigned*)(&xb[(size_t)p0.x * 128 + c0]);
        float w0 = __int_as_float(p0.y);
        a0 = fmaf(w0, bf2f((unsigned short)u0), a0);
        a1 = fmaf(w0, bf2f((unsigned short)(u0 >> 16)), a1);
    }
    float si = isd[n]; si *= si;
    unsigned u = *(const unsigned*)(&xb[(size_t)n * 128 + c0]);
    a0 = fmaf(si, bf2f((unsigned short)u), a0);
    a1 = fmaf(si, bf2f((unsigned short)(u >> 16)), a1);
    *(unsigned*)(&hagg0[(size_t)n * 128 + c0]) = ((unsigned)f2bf(a1) << 16) | f2bf(a0);
}

// ---------------- BN stats over bf16 [N][512] (LDS-reduced, 128 atomics/addr) ----------
__global__ __launch_bounds__(256) void bn_stats2(const unsigned short* __restrict__ h,
                                                 float* __restrict__ stats) {
    __shared__ float sh[4][1024];
    int t = threadIdx.x;
    int wv = t >> 6, l = t & 63;
    int c0 = l * 8;
    float s[8] = {}, q[8] = {};
    for (int n = blockIdx.x * 4 + wv; n < N_NODES; n += STAT_BLOCKS * 4) {
        union { int4 v; unsigned short u[8]; } U;
        U.v = *(const int4*)(&h[(size_t)n * 512 + c0]);
#pragma unroll
        for (int j = 0; j < 8; j++) {
            float x = bf2f(U.u[j]);
            s[j] += x;
            q[j] = fmaf(x, x, q[j]);
        }
    }
#pragma unroll
    for (int j = 0; j < 8; j++) {
        sh[wv][c0 + j] = s[j];
        sh[wv][512 + c0 + j] = q[j];
    }
    __syncthreads();
    for (int i = t; i < 1024; i += 256) {
        float a = sh[0][i] + sh[1][i] + sh[2][i] + sh[3][i];
        atomicAdd(&stats[i], a);
    }
}

// stats -> per-channel affine AB; also re-zeros stats for the next layer
__global__ __launch_bounds__(256) void bn_ab(const float* __restrict__ stats,
                                             const float* __restrict__ g,
                                             const float* __restrict__ be,
                                             float* __restrict__ AB,
                                             float* __restrict__ stats_mut) {
    int t = threadIdx.x;
#pragma unroll
    for (int h = 0; h < 2; h++) {
        int c = t + h * 256;
        float m = stats[c] * (1.0f / N_NODES);
        float var = stats[512 + c] * (1.0f / N_NODES) - m * m;
        float sc = g[c & 255] * rsqrtf(var + BN_EPS);
        AB[c] = sc;
        AB[512 + c] = be[c & 255] - m * sc;
        stats_mut[c] = 0.0f;
        stats_mut[512 + c] = 0.0f;
    }
}

// y = relu(x*A + B), bf16 in/out, 512-wide
__global__ __launch_bounds__(256) void bn_apply(const unsigned short* __restrict__ h,
                                                const float* __restrict__ AB,
                                                unsigned short* __restrict__ outp) {
    int i8 = blockIdx.x * blockDim.x + threadIdx.x;
    if (i8 >= N_NODES * 512 / 8) return;
    int c8 = (i8 & 63) * 8;
    union { int4 v; unsigned short u[8]; } U;
    U.v = *(const int4*)(&h[(size_t)i8 * 8]);
    unsigned short os[8];
#pragma unroll
    for (int j = 0; j < 8; j++) {
        int c = c8 + j;
        float y = fmaf(bf2f(U.u[j]), AB[c], AB[512 + c]);
        os[j] = f2bf(fmaxf(y, 0.0f));
    }
    int4 ov;
    ov.x = (int)(((unsigned)os[1] << 16) | os[0]);
    ov.y = (int)(((unsigned)os[3] << 16) | os[2]);
    ov.z = (int)(((unsigned)os[5] << 16) | os[4]);
    ov.w = (int)(((unsigned)os[7] << 16) | os[6]);
    *(int4*)(&outp[(size_t)i8 * 8]) = ov;
}

// final: hc = relu(bn(h1)) + relu(bn(h2)), bf16 out 256-wide
__global__ __launch_bounds__(256) void bn_apply_final(const unsigned short* __restrict__ h,
                                                      const float* __restrict__ AB,
                                                      unsigned short* __restrict__ hc) {
    int i8 = blockIdx.x * blockDim.x + threadIdx.x;
    if (i8 >= N_NODES * 256 / 8) return;
    int n = i8 >> 5;
    int c8 = (i8 & 31) * 8;
    union { int4 v; unsigned short u[8]; } U1, U2;
    U1.v = *(const int4*)(&h[(size_t)n * 512 + c8]);
    U2.v = *(const int4*)(&h[(size_t)n * 512 + 256 + c8]);
    unsigned short os[8];
#pragma unroll
    for (int j = 0; j < 8; j++) {
        int c = c8 + j;
        float y1 = fmaxf(fmaf(bf2f(U1.u[j]), AB[c], AB[512 + c]), 0.0f);
        int c2 = c + 256;
        float y2 = fmaxf(fmaf(bf2f(U2.u[j]), AB[c2], AB[512 + c2]), 0.0f);
        os[j] = f2bf(y1 + y2);
    }
    int4 ov;
    ov.x = (int)(((unsigned)os[1] << 16) | os[0]);
    ov.y = (int)(((unsigned)os[3] << 16) | os[2]);
    ov.z = (int)(((unsigned)os[5] << 16) | os[4]);
    ov.w = (int)(((unsigned)os[7] << 16) | os[6]);
    *(int4*)(&hc[(size_t)i8 * 8]) = ov;
}

// ---------------- launch ----------------
extern "C" void kernel_launch(void* const* d_in, const int* in_sizes, int n_in,
                              void* d_out, int out_size, void* d_ws, size_t ws_size,
                              hipStream_t stream) {
    const float* x   = (const float*)d_in[0];
    const int*   ei  = (const int*)d_in[1];
    const float* ea  = (const float*)d_in[2];
    const float* W11 = (const float*)d_in[3];
    const float* b11 = (const float*)d_in[4];
    const float* W12 = (const float*)d_in[5];
    const float* b12 = (const float*)d_in[6];
    const float* W13 = (const float*)d_in[7];
    const float* b13 = (const float*)d_in[8];
    const float* W21 = (const float*)d_in[9];
    const float* b21 = (const float*)d_in[10];
    const float* W22 = (const float*)d_in[11];
    const float* b22 = (const float*)d_in[12];
    const float* W23 = (const float*)d_in[13];
    const float* b23 = (const float*)d_in[14];
    const float* g1  = (const float*)d_in[15];
    const float* be1 = (const float*)d_in[16];
    const float* g2  = (const float*)d_in[17];
    const float* be2 = (const float*)d_in[18];
    const float* g3  = (const float*)d_in[19];
    const float* be3 = (const float*)d_in[20];
    const float* Wc1 = (const float*)d_in[21];
    const float* bc1 = (const float*)d_in[22];
    const float* Wc2 = (const float*)d_in[23];
    const float* bc2 = (const float*)d_in[24];
    const float* Wc3 = (const float*)d_in[25];
    const float* bc3 = (const float*)d_in[26];
    const float* Wc4 = (const float*)d_in[27];
    const float* bc4 = (const float*)d_in[28];
    const float* Wc5 = (const float*)d_in[29];
    const float* bc5 = (const float*)d_in[30];

    const int* src = ei;
    const int* dst = ei + N_EDGES;
    float* out = (float*)d_out;

    // ---- workspace carve ----
    char* w = (char*)d_ws;
    auto alloc = [&](size_t bytes) {
        char* p = w;
        w += (bytes + 255) & ~(size_t)255;
        return p;
    };
    float* isd     = (float*)alloc(N_NODES * 4);
    int2*  pk      = (int2*)alloc((size_t)N_EDGES * 8);
    int*   edstA   = (int*)alloc((size_t)N_EDGES * 4);
    int*   eorigA  = (int*)alloc((size_t)N_EDGES * 4);
    int*   counts  = (int*)alloc((N_NODES + 4) * 4);
    int*   offsets = (int*)alloc((N_NODES + 4) * 4);
    int*   bsum    = (int*)alloc(256 * 4);
    int*   boff    = (int*)alloc(256 * 4);
    float* stats   = (float*)alloc(1024 * 4);
    float* AB      = (float*)alloc(1024 * 4);
    unsigned short* W11t = (unsigned short*)alloc(256 * 128 * 2);
    unsigned short* W21t = (unsigned short*)alloc(256 * 128 * 2);
    unsigned short* W12t = (unsigned short*)alloc(256 * 256 * 2);
    unsigned short* W22t = (unsigned short*)alloc(256 * 256 * 2);
    unsigned short* W13t = (unsigned short*)alloc(256 * 256 * 2);
    unsigned short* W23t = (unsigned short*)alloc(256 * 256 * 2);
    unsigned short* WPQt = (unsigned short*)alloc(512 * 256 * 2);
    unsigned short* Wc2t = (unsigned short*)alloc(256 * 256 * 2);
    unsigned short* Wc3t = (unsigned short*)alloc(128 * 256 * 2);
    unsigned short* Wc4t = (unsigned short*)alloc(64 * 128 * 2);
    unsigned short* xb   = (unsigned short*)alloc((size_t)N_NODES * 128 * 2);
    unsigned short* hagg0 = (unsigned short*)alloc((size_t)N_NODES * 128 * 2);
    unsigned short* hb   = (unsigned short*)alloc((size_t)N_NODES * 512 * 2);
    unsigned short* hwb  = (unsigned short*)alloc((size_t)N_NODES * 512 * 2);
    unsigned short* hagg = (unsigned short*)alloc((size_t)N_NODES * 512 * 2);
    unsigned short* hc   = (unsigned short*)alloc((size_t)N_NODES * 256 * 2);
    (void)ws_size;

    // ---- CSR build ----
    zero_i32<<<(N_NODES + 256) / 256, 256, 0, stream>>>(counts, N_NODES + 1);
    count_deg<<<(N_EDGES + 255) / 256, 256, 0, stream>>>(dst, counts);
    isd_kernel<<<(N_NODES + 255) / 256, 256, 0, stream>>>(counts, isd);
    scan_reduce<<<NB_SCAN, 256, 0, stream>>>(counts, bsum);
    scan_tops<<<1, 256, 0, stream>>>(bsum, boff, NB_SCAN, offsets + N_NODES);
    scan_final<<<NB_SCAN, 256, 0, stream>>>(counts, boff, offsets);
    zero_i32<<<(N_NODES + 255) / 256, 256, 0, stream>>>(counts, N_NODES);
    fill_csr<<<(N_EDGES + 255) / 256, 256, 0, stream>>>(src, dst, isd, offsets, counts,
                                                        pk, edstA, eorigA);

    // ---- preconvert (x -> bf16; all 11 weight transposes in ONE dispatch) ----
    conv_f32_bf16<<<(N_NODES * 128 / 4 + 255) / 256, 256, 0, stream>>>(x, xb,
                                                                        N_NODES * 128 / 4);
    WPack wp;
    wp.src[0] = W11; wp.dst[0] = W11t;
    wp.src[1] = W21; wp.dst[1] = W21t;
    wp.src[2] = W12; wp.dst[2] = W12t;
    wp.src[3] = W22; wp.dst[3] = W22t;
    wp.src[4] = W13; wp.dst[4] = W13t;
    wp.src[5] = W23; wp.dst[5] = W23t;
    wp.src[6] = Wc1; wp.dst[6] = WPQt;
    wp.src[7] = Wc1 + 256 * 256; wp.dst[7] = WPQt + 256 * 256;
    wp.src[8] = Wc2; wp.dst[8] = Wc2t;
    wp.src[9] = Wc3; wp.dst[9] = Wc3t;
    wp.src[10] = Wc4; wp.dst[10] = Wc4t;
    prep_weights<<<dim3(256, 11), 256, 0, stream>>>(wp);

    // stats zero (post-poison init; bn_ab re-zeros between layers)
    zero_f32<<<4, 256, 0, stream>>>(stats, 1024);

    int gx_n = (N_NODES + 127) / 128;  // 391

    // ---- layer 0: aggregate x FIRST (GCN linearity), then dual GEMM + bias ----
    aggregate128<<<N_NODES / 4, 256, 0, stream>>>(xb, isd, offsets, pk, hagg0);
    gemm_mfma<128, 1, 0, 1, 1><<<dim3(gx_n, 4), 256, 0, stream>>>(
        hagg0, 128, W11t, b11, hwb, 512, N_NODES, 128, hagg0, W21t, b21);
    bn_stats2<<<STAT_BLOCKS, 256, 0, stream>>>(hwb, stats);
    bn_ab<<<1, 256, 0, stream>>>(stats, g1, be1, AB, stats);
    bn_apply<<<(N_NODES * 512 / 8 + 255) / 256, 256, 0, stream>>>(hwb, AB, hb);

    // ---- layers 1,2 (GEMM -> aggregate -> BN, as before) ----
    const unsigned short* Wat[3] = {W11t, W12t, W13t};
    const unsigned short* Wbt[3] = {W21t, W22t, W23t};
    const float* ba[3] = {b11, b12, b13};
    const float* bb[3] = {b21, b22, b23};
    const float* gs[3] = {g1, g2, g3};
    const float* bes[3] = {be1, be2, be3};

    for (int l = 1; l < 3; l++) {
        gemm_mfma<128, 1, 0, 0, 1><<<dim3(gx_n, 4), 256, 0, stream>>>(
            hb, 512, Wat[l], nullptr, hwb, 512, N_NODES, 256, hb + 256, Wbt[l], nullptr);
        aggregate2<<<N_NODES / 4, 256, 0, stream>>>(hwb, isd, offsets, pk,
                                                    ba[l], bb[l], hagg);
        bn_stats2<<<STAT_BLOCKS, 256, 0, stream>>>(hagg, stats);
        bn_ab<<<1, 256, 0, stream>>>(stats, gs[l], bes[l], AB, stats);
        if (l < 2) {
            bn_apply<<<(N_NODES * 512 / 8 + 255) / 256, 256, 0, stream>>>(hagg, AB, hb);
        } else {
            bn_apply_final<<<(N_NODES * 256 / 8 + 255) / 256, 256, 0, stream>>>(hagg, AB, hc);
        }
    }

    // ---- PQ = hc @ [Wc1_P | Wc1_Q] -> hwb [N][512] bf16 ----
    gemm_mfma<128, 1, 0, 0, 0><<<dim3(gx_n, 4), 256, 0, stream>>>(hc, 256, WPQt, nullptr,
                                                                  hwb, 512, N_NODES, 256,
                                                                  nullptr, nullptr, nullptr);

    // ---- fused edge MLP: one dispatch, all 400K edges ----
    edge_mlp_fused<<<N_EDGES / EPB, 512, 0, stream>>>(
        hwb, pk, edstA, eorigA, ea, Wc1 + 512 * 256, bc1,
        Wc2t, bc2, Wc3t, bc3, Wc4t, bc4, Wc5, bc5, out);
}